// Round 16
// baseline (240.686 us; speedup 1.0000x reference)
//
#include <hip/hip_runtime.h>
#include <hip/hip_bf16.h>

#define B_ 4
#define S_ 2048
#define DIN_ 256
#define DM_ 512
#define H_ 8
#define DH_ 64
#define M_ (B_*S_)

typedef short bf16x8 __attribute__((ext_vector_type(8)));
typedef float f32x4 __attribute__((ext_vector_type(4)));
typedef float f32x16 __attribute__((ext_vector_type(16)));
typedef int v2i __attribute__((ext_vector_type(2)));
typedef unsigned int u32;
typedef unsigned long long u64;

#define MFMA16(a,b,c) __builtin_amdgcn_mfma_f32_16x16x32_bf16((a),(b),(c),0,0,0)
#define MFMA32(a,b,c) __builtin_amdgcn_mfma_f32_32x32x16_bf16((a),(b),(c),0,0,0)

__device__ __forceinline__ unsigned short f2bf(float f) {
  union { float f; unsigned u; } v; v.f = f;
  unsigned r = v.u + 0x7fffu + ((v.u >> 16) & 1u);
  return (unsigned short)(r >> 16);
}
__device__ __forceinline__ f32x4 f32x4_zero() { f32x4 v = {0.f,0.f,0.f,0.f}; return v; }
__device__ __forceinline__ f32x16 f32x16_zero() {
  f32x16 v;
#pragma unroll
  for (int i = 0; i < 16; ++i) v[i] = 0.f;
  return v;
}
__device__ __forceinline__ u32 cvtpk_bf16(float lo, float hi) {
  u32 r; asm("v_cvt_pk_bf16_f32 %0, %1, %2" : "=v"(r) : "v"(lo), "v"(hi)); return r;
}
__device__ __forceinline__ float exp2_asm(float x) {
  float r; asm("v_exp_f32 %0, %1" : "=v"(r) : "v"(x)); return r;
}
__device__ __forceinline__ float max3f(float a, float b, float c) {
  return fmaxf(fmaxf(a, b), c);   // clang fuses to v_max3_f32
}
__device__ __forceinline__ void gload_lds16(const void* g, void* l) {
  __builtin_amdgcn_global_load_lds((const __attribute__((address_space(1))) unsigned int*)g,
                                   (__attribute__((address_space(3))) unsigned int*)l,
                                   16, 0, 0);
}

// ---------------- fp32 -> bf16 cast (two tensors, one launch) ----------------
__global__ void cast_bf16_kernel(const float* __restrict__ inA,
                                 const float* __restrict__ inB,
                                 unsigned short* __restrict__ outA,
                                 unsigned short* __restrict__ outB, int n4) {
  const float* in = blockIdx.y ? inB : inA;
  unsigned short* out = blockIdx.y ? outB : outA;
  int i = blockIdx.x * blockDim.x + threadIdx.x;
  if (i < n4) {
    float4 v = ((const float4*)in)[i];
    ushort4 o;
    o.x = f2bf(v.x); o.y = f2bf(v.y); o.z = f2bf(v.z); o.w = f2bf(v.w);
    ((ushort4*)out)[i] = o;
  }
}

// ---------------- weight prep: W[K][N] fp32 -> Wt[N][K] bf16 ----------------
struct WtDesc {
  const float* src[10];
  unsigned short* dst[10];
  int ks[10];
};
__global__ void prep_w_kernel(WtDesc d) {
  int m = blockIdx.y;
  int ks = d.ks[m];
  int K = 1 << ks;
  int N = 131072 >> ks;
  int i = blockIdx.x * 256 + threadIdx.x;
  int n = i >> ks, k = i & (K - 1);
  d.dst[m][i] = f2bf(d.src[m][(size_t)k * N + n]);
}

// ---------------- tiled GEMM (m97 structure): 128x128 tile, BK=32 ----------------
template<int K, bool RELU>
__global__ __launch_bounds__(256) void gemm_tiled_kernel(
    const unsigned short* __restrict__ A0, const unsigned short* __restrict__ A1,
    const unsigned short* __restrict__ A2,
    const unsigned short* __restrict__ W0, const unsigned short* __restrict__ W1,
    const unsigned short* __restrict__ W2,
    const float* __restrict__ b0, const float* __restrict__ b1, const float* __restrict__ b2,
    unsigned short* __restrict__ o0, unsigned short* __restrict__ o1,
    unsigned short* __restrict__ o2, float scale0, int trsel) {
  const int sel = blockIdx.y >> 2;
  const unsigned short* A = sel == 0 ? A0 : (sel == 1 ? A1 : A2);
  const unsigned short* Wt = sel == 0 ? W0 : (sel == 1 ? W1 : W2);
  const float* bias = sel == 0 ? b0 : (sel == 1 ? b1 : b2);
  unsigned short* out = sel == 0 ? o0 : (sel == 1 ? o1 : o2);
  const float scale = sel == 0 ? scale0 : 1.f;

  const int tid = threadIdx.x;
  const int w = tid >> 6, l = tid & 63;
  const int lr = l & 15, lg = l >> 4;
  const int wr = w >> 1, wc = w & 1;
  const int r0 = blockIdx.x * 128;
  const int c0 = (blockIdx.y & 3) * 128;

  __shared__ __align__(16) unsigned short As[2][128 * 32];
  __shared__ __align__(16) unsigned short Bs[2][128 * 32];

  f32x4 acc[4][4];
#pragma unroll
  for (int m = 0; m < 4; ++m)
#pragma unroll
    for (int n = 0; n < 4; ++n) acc[m][n] = f32x4_zero();

  auto stage = [&](int buf, int k0) {
#pragma unroll
    for (int i = 0; i < 2; ++i) {
      int c = w * 128 + i * 64 + l;      // 512 chunks of 16B each for A and B
      int row = c >> 2, sl = c & 3;
      gload_lds16(A + (size_t)(r0 + row) * K + k0 + sl * 8,
                  &As[buf][(w * 128 + i * 64) * 8]);
      gload_lds16(Wt + (size_t)(c0 + row) * K + k0 + sl * 8,
                  &Bs[buf][(w * 128 + i * 64) * 8]);
    }
  };

  stage(0, 0);
  __syncthreads();

  const int NT = K / 32;                 // 8 or 16, even
  for (int tt = 0; tt < NT; tt += 2) {
#pragma unroll
    for (int u = 0; u < 2; ++u) {
      const int t = tt + u;
      if (t + 1 < NT) stage(u ^ 1, (t + 1) * 32);
      const unsigned short* AB = &As[u][0];
      const unsigned short* BB = &Bs[u][0];
      bf16x8 af[4], bf[4];
#pragma unroll
      for (int m = 0; m < 4; ++m)
        af[m] = *(const bf16x8*)&AB[(wr * 64 + m * 16 + lr) * 32 + lg * 8];
#pragma unroll
      for (int n = 0; n < 4; ++n)
        bf[n] = *(const bf16x8*)&BB[(wc * 64 + n * 16 + lr) * 32 + lg * 8];
#pragma unroll
      for (int m = 0; m < 4; ++m)
#pragma unroll
        for (int n = 0; n < 4; ++n)
          acc[m][n] = MFMA16(af[m], bf[n], acc[m][n]);
      __syncthreads();
    }
  }

  if (sel != trsel) {
#pragma unroll
    for (int n = 0; n < 4; ++n) {
      int col = c0 + wc * 64 + n * 16 + lr;
      float bv = bias[col];
#pragma unroll
      for (int m = 0; m < 4; ++m) {
#pragma unroll
        for (int r = 0; r < 4; ++r) {
          int row = r0 + wr * 64 + m * 16 + lg * 4 + r;
          float v = (acc[m][n][r] + bv) * scale;
          if (RELU) v = fmaxf(v, 0.f);
          out[(size_t)row * DM_ + col] = f2bf(v);
        }
      }
    }
  } else {
    // transposed write: out = Vt [B][DM][S]; block lies in one batch
    const int bb = r0 / S_;
    const int sbase = r0 - bb * S_ + wr * 64 + lg * 4;
#pragma unroll
    for (int n = 0; n < 4; ++n) {
      int col = c0 + wc * 64 + n * 16 + lr;
      float bv = bias[col];
#pragma unroll
      for (int m = 0; m < 4; ++m) {
        ushort4 o;
#pragma unroll
        for (int r = 0; r < 4; ++r) {
          float v = acc[m][n][r] + bv;
          ((unsigned short*)&o)[r] = f2bf(v);
        }
        *(ushort4*)&out[((size_t)bb * DM_ + col) * S_ + sbase + m * 16] = o;
      }
    }
  }
}

// ---------------- GEMM + bias + residual + LayerNorm epilogue (16-row, BK=64) --
template<int NLN>
__global__ __launch_bounds__(256) void gemm_ln_kernel(
    const unsigned short* __restrict__ A,
    const unsigned short* __restrict__ Wt,
    const float* __restrict__ bias,
    const float* __restrict__ res,
    const float* __restrict__ gA, const float* __restrict__ bA,
    const float* __restrict__ gB, const float* __restrict__ bB,
    float* __restrict__ outF,
    unsigned short* __restrict__ outB) {
  const int tid = threadIdx.x;
  const int w = tid >> 6, l = tid & 63;
  const int lr = l & 15, lg = l >> 4;
  const int r0 = blockIdx.x * 16;

  __shared__ __align__(16) unsigned short Bs[2][256 * 64];  // 32KB each
  __shared__ __align__(16) unsigned short As[2][16 * 64];   // 2KB each
  __shared__ float ex[16][4][2];

  f32x4 acc[4];
#pragma unroll
  for (int n = 0; n < 4; ++n) acc[n] = f32x4_zero();

  auto stage = [&](int buf, int k0) {
#pragma unroll
    for (int p = 0; p < 8; ++p) {        // B: 2048 chunks (256 rows x 8 slots)
      int c = (w * 8 + p) * 64 + l;
      int row = c >> 3, sl = c & 7;
      gload_lds16(Wt + (size_t)row * 512 + k0 + ((sl ^ (row & 7)) * 8),
                  &Bs[buf][(w * 8 + p) * 64 * 8]);
    }
    if (w == 0) {                         // A: 128 chunks (16 rows x 8 slots)
#pragma unroll
      for (int p = 0; p < 2; ++p) {
        int c = p * 64 + l;
        int row = c >> 3, sl = c & 7;
        gload_lds16(A + (size_t)(r0 + row) * 512 + k0 + ((sl ^ (row & 7)) * 8),
                    &As[buf][p * 64 * 8]);
      }
    }
  };

  stage(0, 0);
  __syncthreads();

  for (int tt = 0; tt < 8; tt += 2) {
#pragma unroll
    for (int u = 0; u < 2; ++u) {
      const int t = tt + u;
      if (t + 1 < 8) stage(u ^ 1, (t + 1) * 64);
      const unsigned short* BB = &Bs[u][0];
      const unsigned short* AB = &As[u][0];
#pragma unroll
      for (int kk = 0; kk < 2; ++kk) {
        bf16x8 a = *(const bf16x8*)&AB[lr * 64 + (((kk * 4 + lg) ^ (lr & 7)) * 8)];
#pragma unroll
        for (int n = 0; n < 4; ++n) {
          int row = w * 64 + n * 16 + lr;
          bf16x8 b = *(const bf16x8*)&BB[row * 64 + (((kk * 4 + lg) ^ (row & 7)) * 8)];
          acc[n] = MFMA16(a, b, acc[n]);
        }
      }
      __syncthreads();
    }
  }

  f32x4 rv[4];
#pragma unroll
  for (int n = 0; n < 4; ++n) {
    int col = w * 64 + n * 16 + lr;
    float bv = bias[col];
#pragma unroll
    for (int r = 0; r < 4; ++r) {
      int row = r0 + lg * 4 + r;
      float rr = res[(size_t)row * 256 + col];
      rv[n][r] = rr;
      acc[n][r] += bv + rr;
    }
  }

  auto ln_stats = [&](float* mu, float* rs) {
    float s1[4], s2[4];
#pragma unroll
    for (int r = 0; r < 4; ++r) {
      float a1 = 0.f, a2 = 0.f;
#pragma unroll
      for (int n = 0; n < 4; ++n) { float v = acc[n][r]; a1 += v; a2 += v * v; }
#pragma unroll
      for (int off = 1; off < 16; off <<= 1) {
        a1 += __shfl_xor(a1, off);
        a2 += __shfl_xor(a2, off);
      }
      s1[r] = a1; s2[r] = a2;
    }
    if (lr == 0) {
#pragma unroll
      for (int r = 0; r < 4; ++r) {
        ex[lg * 4 + r][w][0] = s1[r];
        ex[lg * 4 + r][w][1] = s2[r];
      }
    }
    __syncthreads();
#pragma unroll
    for (int r = 0; r < 4; ++r) {
      int row = lg * 4 + r;
      float t1 = ex[row][0][0] + ex[row][1][0] + ex[row][2][0] + ex[row][3][0];
      float t2 = ex[row][0][1] + ex[row][1][1] + ex[row][2][1] + ex[row][3][1];
      float m = t1 * (1.f / 256.f);
      float var = t2 * (1.f / 256.f) - m * m;
      mu[r] = m;
      rs[r] = rsqrtf(var + 1e-6f);
    }
  };

  float mu[4], rs[4];
  ln_stats(mu, rs);

  if constexpr (NLN == 2) {
#pragma unroll
    for (int n = 0; n < 4; ++n) {
      int col = w * 64 + n * 16 + lr;
      float g = gA[col], bb = bA[col];
#pragma unroll
      for (int r = 0; r < 4; ++r) {
        float t1 = (acc[n][r] - mu[r]) * rs[r] * g + bb;
        acc[n][r] = rv[n][r] + t1;
      }
    }
    __syncthreads();
    float mu2[4], rs2[4];
    ln_stats(mu2, rs2);
#pragma unroll
    for (int n = 0; n < 4; ++n) {
      int col = w * 64 + n * 16 + lr;
      float g = gB[col], bb = bB[col];
#pragma unroll
      for (int r = 0; r < 4; ++r) {
        int row = r0 + lg * 4 + r;
        float o = (acc[n][r] - mu2[r]) * rs2[r] * g + bb;
        outF[(size_t)row * 256 + col] = o;
        outB[(size_t)row * 256 + col] = f2bf(o);
      }
    }
  } else {
#pragma unroll
    for (int n = 0; n < 4; ++n) {
      int col = w * 64 + n * 16 + lr;
      float g = gA[col], bb = bA[col];
#pragma unroll
      for (int r = 0; r < 4; ++r) {
        int row = r0 + lg * 4 + r;
        float o = (acc[n][r] - mu[r]) * rs[r] * g + bb;
        outF[(size_t)row * 256 + col] = o;
      }
    }
  }
}

// ---------------- Flash attention v11: 2-wave blocks, 4 blocks/CU ----------
// Same per-wave body as v10 (r14/r15 best) but block = 2 waves x 32 q-rows,
// grid 1024 -> 4 blocks/CU (4-way barrier interleave; LDS 4x32KB = 128KB).
// Staging: 16 chunks split over 2 waves (8 each).
template<bool MASKED>
__global__ __launch_bounds__(128) void flash_kernel(
    const unsigned short* __restrict__ Q,
    const unsigned short* __restrict__ Kg,
    const unsigned short* __restrict__ Vt,
    const int* __restrict__ mask,
    unsigned short* __restrict__ O) {
  __shared__ __align__(16) unsigned short lds[2][2][64 * 64];
  const int tid = threadIdx.x;
  const int w = tid >> 6, l = tid & 63;
  const int q32 = l & 31, hi = l >> 5;
  // XCD-grouped: 128 consecutive-per-XCD blocks = 4 (b,h) groups x 32 q-blocks
  const int id = blockIdx.x;
  const int g = (id & 7) * 128 + (id >> 3);
  const int bh = g >> 5, xblk = g & 31;
  const int b = bh >> 3, h = bh & 7;
  const size_t bS = (size_t)b * S_;
  const int q0 = xblk * 64 + w * 32;

  bf16x8 qf[4];
  {
    const unsigned short* qp = Q + (bS + q0 + q32) * DM_ + h * DH_;
#pragma unroll
    for (int c = 0; c < 4; ++c) qf[c] = *(const bf16x8*)(qp + c * 16 + hi * 8);
  }
  bf16x8 ones;
#pragma unroll
  for (int j = 0; j < 8; ++j) ones[j] = (short)0x3F80;   // bf16 1.0

  f32x16 o0 = f32x16_zero(), o1 = f32x16_zero(), lacc = f32x16_zero();
  float m = -1e30f;

  // stage: 16 x 1KB chunks split across 2 waves (4 K + 4 V each)
  auto stage = [&](int buf, int kv0) {
#pragma unroll
    for (int p = 0; p < 4; ++p) {
      int i = w * 4 + p;                 // 0..7
      int row = i * 8 + (l >> 3);
      int slot = l & 7;
      gload_lds16(Kg + (bS + kv0 + row) * DM_ + h * DH_ + ((slot ^ (row & 7)) * 8),
                  &lds[buf][0][i * 8 * 64]);
      gload_lds16(Vt + ((size_t)b * DM_ + h * DH_ + row) * S_ + kv0 + ((slot ^ (row & 7)) * 8),
                  &lds[buf][1][i * 8 * 64]);
    }
  };

  stage(0, 0);
  int mvCur = 1;
  if (MASKED) mvCur = mask[bS + l];
  __syncthreads();

  const int NT = S_ / 64;   // 32, even
  for (int tt = 0; tt < NT; tt += 2) {
#pragma unroll
    for (int u = 0; u < 2; ++u) {        // u = buffer index (compile-time)
      const int t = tt + u;
      int mvNext = 1;
      if (t + 1 < NT) {
        stage(u ^ 1, (t + 1) * 64);
        if (MASKED) mvNext = mask[bS + (t + 1) * 64 + l];
      }
      u64 bits = 0;
      if (MASKED) bits = __ballot(mvCur != 0);

      const unsigned short* KB = &lds[u][0][0];
      const unsigned short* VB = &lds[u][1][0];

      f32x16 sc[2];
      __builtin_amdgcn_s_setprio(1);
#pragma unroll
      for (int kt = 0; kt < 2; ++kt) {
        f32x16 s = f32x16_zero();
#pragma unroll
        for (int c = 0; c < 4; ++c) {
          int row = kt * 32 + q32;
          int slot = (c * 2 + hi) ^ (row & 7);
          bf16x8 kf = *(const bf16x8*)&KB[row * 64 + slot * 8];
          s = MFMA32(kf, qf[c], s);
        }
        if (MASKED) {
          u32 valid = (u32)(bits >> (kt * 32 + q32)) & 1u;
          u32 mfw = valid ? 0u : 0xC080C080u;   // bf16 -4.0 pair; 16 k-slots -> -64
          union { u32 u[4]; bf16x8 v; } mf;
          mf.u[0] = mfw; mf.u[1] = mfw; mf.u[2] = mfw; mf.u[3] = mfw;
          s = MFMA32(mf.v, ones, s);
        }
        sc[kt] = s;
      }
      __builtin_amdgcn_s_setprio(0);

      float tm;
      {
        float r01;
#pragma unroll
        for (int kt = 0; kt < 2; ++kt) {
          float m0 = max3f(sc[kt][0], sc[kt][1], sc[kt][2]);
          float m1 = max3f(sc[kt][3], sc[kt][4], sc[kt][5]);
          float m2 = max3f(sc[kt][6], sc[kt][7], sc[kt][8]);
          float m3 = max3f(sc[kt][9], sc[kt][10], sc[kt][11]);
          float m4 = max3f(sc[kt][12], sc[kt][13], sc[kt][14]);
          float r = fmaxf(max3f(max3f(m0, m1, m2), m3, m4), sc[kt][15]);
          if (kt == 0) r01 = r; else r01 = fmaxf(r01, r);
        }
        tm = fmaxf(r01, __shfl_xor(r01, 32));
      }

      if (__any(tm > m + 11.5f)) {       // defer-max, THR = 11.5 bits
        float mn = fmaxf(m, tm);
        float fac = exp2_asm(m - mn);
        m = mn;
#pragma unroll
        for (int i = 0; i < 16; ++i) {
          int rq = (i & 3) + 8 * (i >> 2) + 4 * hi;
          float fr = __shfl(fac, rq);
          o0[i] *= fr;
          o1[i] *= fr;
          lacc[i] *= fr;
        }
      }

      float pv[2][16];
#pragma unroll
      for (int kt = 0; kt < 2; ++kt)
#pragma unroll
        for (int i = 0; i < 16; ++i) pv[kt][i] = exp2_asm(sc[kt][i] - m);

      u32 w8[2][8];
#pragma unroll
      for (int kt = 0; kt < 2; ++kt)
#pragma unroll
        for (int j = 0; j < 8; ++j)
          w8[kt][j] = cvtpk_bf16(pv[kt][2 * j], pv[kt][2 * j + 1]);

      __builtin_amdgcn_s_setprio(1);
#pragma unroll
      for (int kt = 0; kt < 2; ++kt) {
#pragma unroll
        for (int kc = 0; kc < 2; ++kc) {
          v2i r0 = __builtin_amdgcn_permlane32_swap((int)w8[kt][4 * kc + 0],
                                                    (int)w8[kt][4 * kc + 2], false, false);
          v2i r1 = __builtin_amdgcn_permlane32_swap((int)w8[kt][4 * kc + 1],
                                                    (int)w8[kt][4 * kc + 3], false, false);
          union { u32 u[4]; bf16x8 v; } af;
          af.u[0] = (u32)r0.x; af.u[1] = (u32)r1.x; af.u[2] = (u32)r0.y; af.u[3] = (u32)r1.y;
          {
            int row = q32;
            int slot = (kt * 4 + kc * 2 + hi) ^ (row & 7);
            bf16x8 vf = *(const bf16x8*)&VB[row * 64 + slot * 8];
            o0 = MFMA32(af.v, vf, o0);
          }
          {
            int row = 32 + q32;
            int slot = (kt * 4 + kc * 2 + hi) ^ (row & 7);
            bf16x8 vf = *(const bf16x8*)&VB[row * 64 + slot * 8];
            o1 = MFMA32(af.v, vf, o1);
          }
          lacc = MFMA32(af.v, ones, lacc);   // row-sum on the MFMA pipe
        }
      }
      __builtin_amdgcn_s_setprio(0);
      __syncthreads();
      mvCur = mvNext;
    }
  }

#pragma unroll
  for (int i = 0; i < 16; ++i) {
    int rq = (i & 3) + 8 * (i >> 2) + 4 * hi;
    float inv = __builtin_amdgcn_rcpf(lacc[i]);
    int row = q0 + rq;
    O[(bS + row) * DM_ + h * DH_ + q32] = f2bf(o0[i] * inv);
    O[(bS + row) * DM_ + h * DH_ + 32 + q32] = f2bf(o1[i] * inv);
  }
}

// ---------------- host ----------------
extern "C" void kernel_launch(void* const* d_in, const int* in_sizes, int n_in,
                              void* d_out, int out_size, void* d_ws, size_t ws_size,
                              hipStream_t stream) {
  const float* x     = (const float*)d_in[0];
  const float* eo    = (const float*)d_in[1];
  const int*   tmask = (const int*)d_in[2];
  const float* m1_wq = (const float*)d_in[4];  const float* m1_bq = (const float*)d_in[5];
  const float* m1_wk = (const float*)d_in[6];  const float* m1_bk = (const float*)d_in[7];
  const float* m1_wv = (const float*)d_in[8];  const float* m1_bv = (const float*)d_in[9];
  const float* m1_w2 = (const float*)d_in[10]; const float* m1_b2 = (const float*)d_in[11];
  const float* m1_g  = (const float*)d_in[12]; const float* m1_b  = (const float*)d_in[13];
  const float* m2_wq = (const float*)d_in[14]; const float* m2_bq = (const float*)d_in[15];
  const float* m2_wk = (const float*)d_in[16]; const float* m2_bk = (const float*)d_in[17];
  const float* m2_wv = (const float*)d_in[18]; const float* m2_bv = (const float*)d_in[19];
  const float* m2_w2 = (const float*)d_in[20]; const float* m2_b2 = (const float*)d_in[21];
  const float* m2_g  = (const float*)d_in[22]; const float* m2_b  = (const float*)d_in[23];
  const float* ln1_g = (const float*)d_in[24]; const float* ln1_b = (const float*)d_in[25];
  const float* ln2_g = (const float*)d_in[26]; const float* ln2_b = (const float*)d_in[27];
  const float* ln3_g = (const float*)d_in[28]; const float* ln3_b = (const float*)d_in[29];
  const float* f_w1  = (const float*)d_in[30]; const float* f_b1  = (const float*)d_in[31];
  const float* f_w2  = (const float*)d_in[32]; const float* f_b2  = (const float*)d_in[33];

  char* ws = (char*)d_ws;
  size_t off = 0;
  auto alloc = [&](size_t bytes) -> void* {
    void* p = ws + off;
    off += (bytes + 255) & ~(size_t)255;
    return p;
  };
  unsigned short* wt[10];
  for (int i = 0; i < 10; ++i) wt[i] = (unsigned short*)alloc(131072 * 2);
  unsigned short* xb  = (unsigned short*)alloc((size_t)M_ * DIN_ * 2);
  unsigned short* eb  = (unsigned short*)alloc((size_t)M_ * DIN_ * 2);
  unsigned short* Qb  = (unsigned short*)alloc((size_t)M_ * DM_ * 2);
  unsigned short* Kb  = (unsigned short*)alloc((size_t)M_ * DM_ * 2);
  unsigned short* AOb = (unsigned short*)alloc((size_t)M_ * DM_ * 2);
  float*          X1  = (float*)alloc((size_t)M_ * DIN_ * 4);
  unsigned short* X1b = (unsigned short*)alloc((size_t)M_ * DIN_ * 2);
  float*          X2  = (float*)alloc((size_t)M_ * DIN_ * 4);
  unsigned short* X2b = (unsigned short*)alloc((size_t)M_ * DIN_ * 2);
  unsigned short* VtA = (unsigned short*)alloc((size_t)M_ * DM_ * 2);  // [B][512][2048]
  unsigned short* VtB = (unsigned short*)alloc((size_t)M_ * DM_ * 2);
  unsigned short* Hb  = Qb;                      // dead by FFN stage

  int n4 = M_ * DIN_ / 4;
  cast_bf16_kernel<<<dim3(n4 / 256, 2), 256, 0, stream>>>(x, eo, xb, eb, n4);

  WtDesc wd;
  const float* srcs[10] = {m1_wq, m1_wk, m1_wv, m1_w2, m2_wq, m2_wk, m2_wv, m2_w2, f_w1, f_w2};
  int kss[10]           = {8,     8,     8,     9,     8,     8,     8,     9,     8,    9};
  for (int i = 0; i < 10; ++i) { wd.src[i] = srcs[i]; wd.dst[i] = wt[i]; wd.ks[i] = kss[i]; }
  prep_w_kernel<<<dim3(512, 10), 256, 0, stream>>>(wd);

  const int FG = (S_ / 64) * H_ * B_;    // 1024 flat blocks, XCD-grouped in-kernel
  const float QSCALE = 0.125f * 1.44269504088896f;   // 1/sqrt(DH) * log2(e)

  // ---- stage A: masked self-attention (V written transposed by GEMM) ----
  gemm_tiled_kernel<256, false><<<dim3(M_ / 128, 12), 256, 0, stream>>>(
      xb, xb, xb, wt[0], wt[1], wt[2], m1_bq, m1_bk, m1_bv, Qb, Kb, VtA, QSCALE, 2);
  flash_kernel<true><<<FG, 128, 0, stream>>>(Qb, Kb, VtA, tmask, AOb);
  gemm_ln_kernel<2><<<M_ / 16, 256, 0, stream>>>(AOb, wt[3], m1_b2, x,
                                                 m1_g, m1_b, ln1_g, ln1_b, X1, X1b);
  // ---- stage B: cross-attention; Q from X1b, K/V from eb (V transposed) ----
  gemm_tiled_kernel<256, false><<<dim3(M_ / 128, 12), 256, 0, stream>>>(
      X1b, eb, eb, wt[4], wt[5], wt[6], m2_bq, m2_bk, m2_bv, Qb, Kb, VtB, QSCALE, 2);
  flash_kernel<false><<<FG, 128, 0, stream>>>(Qb, Kb, VtB, nullptr, AOb);
  gemm_ln_kernel<2><<<M_ / 16, 256, 0, stream>>>(AOb, wt[7], m2_b2, X1,
                                                 m2_g, m2_b, ln2_g, ln2_b, X2, X2b);
  // ---- stage C: FFN ----
  gemm_tiled_kernel<256, true><<<dim3(M_ / 128, 4), 256, 0, stream>>>(
      X2b, X2b, X2b, wt[8], wt[8], wt[8], f_b1, f_b1, f_b1, Hb, Hb, Hb, 1.f, -1);
  gemm_ln_kernel<1><<<M_ / 16, 256, 0, stream>>>(Hb, wt[9], f_b2, X2,
                                                 ln3_g, ln3_b, nullptr, nullptr,
                                                 (float*)d_out, nullptr);
}

// Round 17
// 196.772 us; speedup vs baseline: 1.2232x; 1.2232x over previous
//
#include <hip/hip_runtime.h>
#include <hip/hip_bf16.h>

#define B_ 4
#define S_ 2048
#define DIN_ 256
#define DM_ 512
#define H_ 8
#define DH_ 64
#define M_ (B_*S_)

typedef short bf16x8 __attribute__((ext_vector_type(8)));
typedef float f32x4 __attribute__((ext_vector_type(4)));
typedef float f32x16 __attribute__((ext_vector_type(16)));
typedef int v2i __attribute__((ext_vector_type(2)));
typedef unsigned int u32;
typedef unsigned long long u64;

#define MFMA16(a,b,c) __builtin_amdgcn_mfma_f32_16x16x32_bf16((a),(b),(c),0,0,0)
#define MFMA32(a,b,c) __builtin_amdgcn_mfma_f32_32x32x16_bf16((a),(b),(c),0,0,0)

__device__ __forceinline__ unsigned short f2bf(float f) {
  union { float f; unsigned u; } v; v.f = f;
  unsigned r = v.u + 0x7fffu + ((v.u >> 16) & 1u);
  return (unsigned short)(r >> 16);
}
__device__ __forceinline__ f32x4 f32x4_zero() { f32x4 v = {0.f,0.f,0.f,0.f}; return v; }
__device__ __forceinline__ f32x16 f32x16_zero() {
  f32x16 v;
#pragma unroll
  for (int i = 0; i < 16; ++i) v[i] = 0.f;
  return v;
}
__device__ __forceinline__ u32 cvtpk_bf16(float lo, float hi) {
  u32 r; asm("v_cvt_pk_bf16_f32 %0, %1, %2" : "=v"(r) : "v"(lo), "v"(hi)); return r;
}
__device__ __forceinline__ float exp2_asm(float x) {
  float r; asm("v_exp_f32 %0, %1" : "=v"(r) : "v"(x)); return r;
}
__device__ __forceinline__ float max3f(float a, float b, float c) {
  return fmaxf(fmaxf(a, b), c);   // clang fuses to v_max3_f32
}
__device__ __forceinline__ void gload_lds16(const void* g, void* l) {
  __builtin_amdgcn_global_load_lds((const __attribute__((address_space(1))) unsigned int*)g,
                                   (__attribute__((address_space(3))) unsigned int*)l,
                                   16, 0, 0);
}

// ---------------- fp32 -> bf16 cast (two tensors, one launch) ----------------
__global__ void cast_bf16_kernel(const float* __restrict__ inA,
                                 const float* __restrict__ inB,
                                 unsigned short* __restrict__ outA,
                                 unsigned short* __restrict__ outB, int n4) {
  const float* in = blockIdx.y ? inB : inA;
  unsigned short* out = blockIdx.y ? outB : outA;
  int i = blockIdx.x * blockDim.x + threadIdx.x;
  if (i < n4) {
    float4 v = ((const float4*)in)[i];
    ushort4 o;
    o.x = f2bf(v.x); o.y = f2bf(v.y); o.z = f2bf(v.z); o.w = f2bf(v.w);
    ((ushort4*)out)[i] = o;
  }
}

// ---------------- weight prep: W[K][N] fp32 -> Wt[N][K] bf16 ----------------
struct WtDesc {
  const float* src[10];
  unsigned short* dst[10];
  int ks[10];
};
__global__ void prep_w_kernel(WtDesc d) {
  int m = blockIdx.y;
  int ks = d.ks[m];
  int K = 1 << ks;
  int N = 131072 >> ks;
  int i = blockIdx.x * 256 + threadIdx.x;
  int n = i >> ks, k = i & (K - 1);
  d.dst[m][i] = f2bf(d.src[m][(size_t)k * N + n]);
}

// ---------------- tiled GEMM (m97 structure): 128x128 tile, BK=32 ----------------
// Per-sel A pointer so independent GEMMs share one launch. sel == trsel
// writes its output in transposed Vt layout [B][DM][S] (fused V-transpose).
// K-loop parity-unrolled: compile-time LDS buffer index.
template<int K, bool RELU>
__global__ __launch_bounds__(256) void gemm_tiled_kernel(
    const unsigned short* __restrict__ A0, const unsigned short* __restrict__ A1,
    const unsigned short* __restrict__ A2,
    const unsigned short* __restrict__ W0, const unsigned short* __restrict__ W1,
    const unsigned short* __restrict__ W2,
    const float* __restrict__ b0, const float* __restrict__ b1, const float* __restrict__ b2,
    unsigned short* __restrict__ o0, unsigned short* __restrict__ o1,
    unsigned short* __restrict__ o2, float scale0, int trsel) {
  const int sel = blockIdx.y >> 2;
  const unsigned short* A = sel == 0 ? A0 : (sel == 1 ? A1 : A2);
  const unsigned short* Wt = sel == 0 ? W0 : (sel == 1 ? W1 : W2);
  const float* bias = sel == 0 ? b0 : (sel == 1 ? b1 : b2);
  unsigned short* out = sel == 0 ? o0 : (sel == 1 ? o1 : o2);
  const float scale = sel == 0 ? scale0 : 1.f;

  const int tid = threadIdx.x;
  const int w = tid >> 6, l = tid & 63;
  const int lr = l & 15, lg = l >> 4;
  const int wr = w >> 1, wc = w & 1;
  const int r0 = blockIdx.x * 128;
  const int c0 = (blockIdx.y & 3) * 128;

  __shared__ __align__(16) unsigned short As[2][128 * 32];
  __shared__ __align__(16) unsigned short Bs[2][128 * 32];

  f32x4 acc[4][4];
#pragma unroll
  for (int m = 0; m < 4; ++m)
#pragma unroll
    for (int n = 0; n < 4; ++n) acc[m][n] = f32x4_zero();

  auto stage = [&](int buf, int k0) {
#pragma unroll
    for (int i = 0; i < 2; ++i) {
      int c = w * 128 + i * 64 + l;      // 512 chunks of 16B each for A and B
      int row = c >> 2, sl = c & 3;
      gload_lds16(A + (size_t)(r0 + row) * K + k0 + sl * 8,
                  &As[buf][(w * 128 + i * 64) * 8]);
      gload_lds16(Wt + (size_t)(c0 + row) * K + k0 + sl * 8,
                  &Bs[buf][(w * 128 + i * 64) * 8]);
    }
  };

  stage(0, 0);
  __syncthreads();

  const int NT = K / 32;                 // 8 or 16, even
  for (int tt = 0; tt < NT; tt += 2) {
#pragma unroll
    for (int u = 0; u < 2; ++u) {
      const int t = tt + u;
      if (t + 1 < NT) stage(u ^ 1, (t + 1) * 32);
      const unsigned short* AB = &As[u][0];
      const unsigned short* BB = &Bs[u][0];
      bf16x8 af[4], bf[4];
#pragma unroll
      for (int m = 0; m < 4; ++m)
        af[m] = *(const bf16x8*)&AB[(wr * 64 + m * 16 + lr) * 32 + lg * 8];
#pragma unroll
      for (int n = 0; n < 4; ++n)
        bf[n] = *(const bf16x8*)&BB[(wc * 64 + n * 16 + lr) * 32 + lg * 8];
#pragma unroll
      for (int m = 0; m < 4; ++m)
#pragma unroll
        for (int n = 0; n < 4; ++n)
          acc[m][n] = MFMA16(af[m], bf[n], acc[m][n]);
      __syncthreads();
    }
  }

  if (sel != trsel) {
#pragma unroll
    for (int n = 0; n < 4; ++n) {
      int col = c0 + wc * 64 + n * 16 + lr;
      float bv = bias[col];
#pragma unroll
      for (int m = 0; m < 4; ++m) {
#pragma unroll
        for (int r = 0; r < 4; ++r) {
          int row = r0 + wr * 64 + m * 16 + lg * 4 + r;
          float v = (acc[m][n][r] + bv) * scale;
          if (RELU) v = fmaxf(v, 0.f);
          out[(size_t)row * DM_ + col] = f2bf(v);
        }
      }
    }
  } else {
    // transposed write: out = Vt [B][DM][S]; block lies in one batch
    const int bb = r0 / S_;
    const int sbase = r0 - bb * S_ + wr * 64 + lg * 4;
#pragma unroll
    for (int n = 0; n < 4; ++n) {
      int col = c0 + wc * 64 + n * 16 + lr;
      float bv = bias[col];
#pragma unroll
      for (int m = 0; m < 4; ++m) {
        ushort4 o;
#pragma unroll
        for (int r = 0; r < 4; ++r) {
          float v = acc[m][n][r] + bv;
          ((unsigned short*)&o)[r] = f2bf(v);
        }
        *(ushort4*)&out[((size_t)bb * DM_ + col) * S_ + sbase + m * 16] = o;
      }
    }
  }
}

// ---------------- GEMM + bias + residual + LayerNorm epilogue (16-row, BK=64) --
// Block 256 = 4 waves; wave w owns cols [w*64, w*64+64). 8 k-iterations of
// BK=64 (8 MFMA/wave per barrier), parity-unrolled. 128B LDS rows XOR-swizzled.
template<int NLN>
__global__ __launch_bounds__(256) void gemm_ln_kernel(
    const unsigned short* __restrict__ A,
    const unsigned short* __restrict__ Wt,
    const float* __restrict__ bias,
    const float* __restrict__ res,
    const float* __restrict__ gA, const float* __restrict__ bA,
    const float* __restrict__ gB, const float* __restrict__ bB,
    float* __restrict__ outF,
    unsigned short* __restrict__ outB) {
  const int tid = threadIdx.x;
  const int w = tid >> 6, l = tid & 63;
  const int lr = l & 15, lg = l >> 4;
  const int r0 = blockIdx.x * 16;

  __shared__ __align__(16) unsigned short Bs[2][256 * 64];  // 32KB each
  __shared__ __align__(16) unsigned short As[2][16 * 64];   // 2KB each
  __shared__ float ex[16][4][2];

  f32x4 acc[4];
#pragma unroll
  for (int n = 0; n < 4; ++n) acc[n] = f32x4_zero();

  auto stage = [&](int buf, int k0) {
#pragma unroll
    for (int p = 0; p < 8; ++p) {        // B: 2048 chunks (256 rows x 8 slots)
      int c = (w * 8 + p) * 64 + l;
      int row = c >> 3, sl = c & 7;
      gload_lds16(Wt + (size_t)row * 512 + k0 + ((sl ^ (row & 7)) * 8),
                  &Bs[buf][(w * 8 + p) * 64 * 8]);
    }
    if (w == 0) {                         // A: 128 chunks (16 rows x 8 slots)
#pragma unroll
      for (int p = 0; p < 2; ++p) {
        int c = p * 64 + l;
        int row = c >> 3, sl = c & 7;
        gload_lds16(A + (size_t)(r0 + row) * 512 + k0 + ((sl ^ (row & 7)) * 8),
                    &As[buf][p * 64 * 8]);
      }
    }
  };

  stage(0, 0);
  __syncthreads();

  for (int tt = 0; tt < 8; tt += 2) {
#pragma unroll
    for (int u = 0; u < 2; ++u) {
      const int t = tt + u;
      if (t + 1 < 8) stage(u ^ 1, (t + 1) * 64);
      const unsigned short* BB = &Bs[u][0];
      const unsigned short* AB = &As[u][0];
#pragma unroll
      for (int kk = 0; kk < 2; ++kk) {
        bf16x8 a = *(const bf16x8*)&AB[lr * 64 + (((kk * 4 + lg) ^ (lr & 7)) * 8)];
#pragma unroll
        for (int n = 0; n < 4; ++n) {
          int row = w * 64 + n * 16 + lr;
          bf16x8 b = *(const bf16x8*)&BB[row * 64 + (((kk * 4 + lg) ^ (row & 7)) * 8)];
          acc[n] = MFMA16(a, b, acc[n]);
        }
      }
      __syncthreads();
    }
  }

  f32x4 rv[4];
#pragma unroll
  for (int n = 0; n < 4; ++n) {
    int col = w * 64 + n * 16 + lr;
    float bv = bias[col];
#pragma unroll
    for (int r = 0; r < 4; ++r) {
      int row = r0 + lg * 4 + r;
      float rr = res[(size_t)row * 256 + col];
      rv[n][r] = rr;
      acc[n][r] += bv + rr;
    }
  }

  auto ln_stats = [&](float* mu, float* rs) {
    float s1[4], s2[4];
#pragma unroll
    for (int r = 0; r < 4; ++r) {
      float a1 = 0.f, a2 = 0.f;
#pragma unroll
      for (int n = 0; n < 4; ++n) { float v = acc[n][r]; a1 += v; a2 += v * v; }
#pragma unroll
      for (int off = 1; off < 16; off <<= 1) {
        a1 += __shfl_xor(a1, off);
        a2 += __shfl_xor(a2, off);
      }
      s1[r] = a1; s2[r] = a2;
    }
    if (lr == 0) {
#pragma unroll
      for (int r = 0; r < 4; ++r) {
        ex[lg * 4 + r][w][0] = s1[r];
        ex[lg * 4 + r][w][1] = s2[r];
      }
    }
    __syncthreads();
#pragma unroll
    for (int r = 0; r < 4; ++r) {
      int row = lg * 4 + r;
      float t1 = ex[row][0][0] + ex[row][1][0] + ex[row][2][0] + ex[row][3][0];
      float t2 = ex[row][0][1] + ex[row][1][1] + ex[row][2][1] + ex[row][3][1];
      float m = t1 * (1.f / 256.f);
      float var = t2 * (1.f / 256.f) - m * m;
      mu[r] = m;
      rs[r] = rsqrtf(var + 1e-6f);
    }
  };

  float mu[4], rs[4];
  ln_stats(mu, rs);

  if constexpr (NLN == 2) {
#pragma unroll
    for (int n = 0; n < 4; ++n) {
      int col = w * 64 + n * 16 + lr;
      float g = gA[col], bb = bA[col];
#pragma unroll
      for (int r = 0; r < 4; ++r) {
        float t1 = (acc[n][r] - mu[r]) * rs[r] * g + bb;
        acc[n][r] = rv[n][r] + t1;
      }
    }
    __syncthreads();
    float mu2[4], rs2[4];
    ln_stats(mu2, rs2);
#pragma unroll
    for (int n = 0; n < 4; ++n) {
      int col = w * 64 + n * 16 + lr;
      float g = gB[col], bb = bB[col];
#pragma unroll
      for (int r = 0; r < 4; ++r) {
        int row = r0 + lg * 4 + r;
        float o = (acc[n][r] - mu2[r]) * rs2[r] * g + bb;
        outF[(size_t)row * 256 + col] = o;
        outB[(size_t)row * 256 + col] = f2bf(o);
      }
    }
  } else {
#pragma unroll
    for (int n = 0; n < 4; ++n) {
      int col = w * 64 + n * 16 + lr;
      float g = gA[col], bb = bA[col];
#pragma unroll
      for (int r = 0; r < 4; ++r) {
        int row = r0 + lg * 4 + r;
        float o = (acc[n][r] - mu[r]) * rs[r] * g + bb;
        outF[(size_t)row * 256 + col] = o;
      }
    }
  }
}

// ---------------- Flash attention v10 (r15, measured best: 58.7us) ----------
// Block 256 = 4 waves each owning 32 q-rows, shared double-buffered 64-key
// K/V tiles (32KB LDS). Flat grid 512 with XCD-grouped mapping. Tile loop
// parity-unrolled. Mask via rank-1 MFMA bias; rowsum on the MFMA pipe.
template<bool MASKED>
__global__ __launch_bounds__(256) void flash_kernel(
    const unsigned short* __restrict__ Q,
    const unsigned short* __restrict__ Kg,
    const unsigned short* __restrict__ Vt,
    const int* __restrict__ mask,
    unsigned short* __restrict__ O) {
  __shared__ __align__(16) unsigned short lds[2][2][64 * 64];
  const int tid = threadIdx.x;
  const int w = tid >> 6, l = tid & 63;
  const int q32 = l & 31, hi = l >> 5;
  const int id = blockIdx.x;
  const int g = (id & 7) * 64 + (id >> 3);
  const int bh = g >> 4, xblk = g & 15;
  const int b = bh >> 3, h = bh & 7;
  const size_t bS = (size_t)b * S_;
  const int q0 = xblk * 128 + w * 32;

  bf16x8 qf[4];
  {
    const unsigned short* qp = Q + (bS + q0 + q32) * DM_ + h * DH_;
#pragma unroll
    for (int c = 0; c < 4; ++c) qf[c] = *(const bf16x8*)(qp + c * 16 + hi * 8);
  }
  bf16x8 ones;
#pragma unroll
  for (int j = 0; j < 8; ++j) ones[j] = (short)0x3F80;   // bf16 1.0

  f32x16 o0 = f32x16_zero(), o1 = f32x16_zero(), lacc = f32x16_zero();
  float m = -1e30f;

  auto stage = [&](int buf, int kv0) {
#pragma unroll
    for (int p = 0; p < 2; ++p) {
      int i = w * 2 + p;                 // 0..7
      int row = i * 8 + (l >> 3);
      int slot = l & 7;
      gload_lds16(Kg + (bS + kv0 + row) * DM_ + h * DH_ + ((slot ^ (row & 7)) * 8),
                  &lds[buf][0][i * 8 * 64]);
      gload_lds16(Vt + ((size_t)b * DM_ + h * DH_ + row) * S_ + kv0 + ((slot ^ (row & 7)) * 8),
                  &lds[buf][1][i * 8 * 64]);
    }
  };

  stage(0, 0);
  int mvCur = 1;
  if (MASKED) mvCur = mask[bS + l];
  __syncthreads();

  const int NT = S_ / 64;   // 32, even
  for (int tt = 0; tt < NT; tt += 2) {
#pragma unroll
    for (int u = 0; u < 2; ++u) {        // u = buffer index (compile-time)
      const int t = tt + u;
      int mvNext = 1;
      if (t + 1 < NT) {
        stage(u ^ 1, (t + 1) * 64);
        if (MASKED) mvNext = mask[bS + (t + 1) * 64 + l];
      }
      u64 bits = 0;
      if (MASKED) bits = __ballot(mvCur != 0);

      const unsigned short* KB = &lds[u][0][0];
      const unsigned short* VB = &lds[u][1][0];

      f32x16 sc[2];
      __builtin_amdgcn_s_setprio(1);
#pragma unroll
      for (int kt = 0; kt < 2; ++kt) {
        f32x16 s = f32x16_zero();
#pragma unroll
        for (int c = 0; c < 4; ++c) {
          int row = kt * 32 + q32;
          int slot = (c * 2 + hi) ^ (row & 7);
          bf16x8 kf = *(const bf16x8*)&KB[row * 64 + slot * 8];
          s = MFMA32(kf, qf[c], s);
        }
        if (MASKED) {
          u32 valid = (u32)(bits >> (kt * 32 + q32)) & 1u;
          u32 mfw = valid ? 0u : 0xC080C080u;   // bf16 -4.0 pair; 16 k-slots -> -64
          union { u32 u[4]; bf16x8 v; } mf;
          mf.u[0] = mfw; mf.u[1] = mfw; mf.u[2] = mfw; mf.u[3] = mfw;
          s = MFMA32(mf.v, ones, s);
        }
        sc[kt] = s;
      }
      __builtin_amdgcn_s_setprio(0);

      float tm;
      {
        float r01;
#pragma unroll
        for (int kt = 0; kt < 2; ++kt) {
          float m0 = max3f(sc[kt][0], sc[kt][1], sc[kt][2]);
          float m1 = max3f(sc[kt][3], sc[kt][4], sc[kt][5]);
          float m2 = max3f(sc[kt][6], sc[kt][7], sc[kt][8]);
          float m3 = max3f(sc[kt][9], sc[kt][10], sc[kt][11]);
          float m4 = max3f(sc[kt][12], sc[kt][13], sc[kt][14]);
          float r = fmaxf(max3f(max3f(m0, m1, m2), m3, m4), sc[kt][15]);
          if (kt == 0) r01 = r; else r01 = fmaxf(r01, r);
        }
        tm = fmaxf(r01, __shfl_xor(r01, 32));
      }

      if (__any(tm > m + 11.5f)) {       // defer-max, THR = 11.5 bits
        float mn = fmaxf(m, tm);
        float fac = exp2_asm(m - mn);
        m = mn;
#pragma unroll
        for (int i = 0; i < 16; ++i) {
          int rq = (i & 3) + 8 * (i >> 2) + 4 * hi;
          float fr = __shfl(fac, rq);
          o0[i] *= fr;
          o1[i] *= fr;
          lacc[i] *= fr;
        }
      }

      float pv[2][16];
#pragma unroll
      for (int kt = 0; kt < 2; ++kt)
#pragma unroll
        for (int i = 0; i < 16; ++i) pv[kt][i] = exp2_asm(sc[kt][i] - m);

      u32 w8[2][8];
#pragma unroll
      for (int kt = 0; kt < 2; ++kt)
#pragma unroll
        for (int j = 0; j < 8; ++j)
          w8[kt][j] = cvtpk_bf16(pv[kt][2 * j], pv[kt][2 * j + 1]);

      __builtin_amdgcn_s_setprio(1);
#pragma unroll
      for (int kt = 0; kt < 2; ++kt) {
#pragma unroll
        for (int kc = 0; kc < 2; ++kc) {
          v2i r0 = __builtin_amdgcn_permlane32_swap((int)w8[kt][4 * kc + 0],
                                                    (int)w8[kt][4 * kc + 2], false, false);
          v2i r1 = __builtin_amdgcn_permlane32_swap((int)w8[kt][4 * kc + 1],
                                                    (int)w8[kt][4 * kc + 3], false, false);
          union { u32 u[4]; bf16x8 v; } af;
          af.u[0] = (u32)r0.x; af.u[1] = (u32)r1.x; af.u[2] = (u32)r0.y; af.u[3] = (u32)r1.y;
          {
            int row = q32;
            int slot = (kt * 4 + kc * 2 + hi) ^ (row & 7);
            bf16x8 vf = *(const bf16x8*)&VB[row * 64 + slot * 8];
            o0 = MFMA32(af.v, vf, o0);
          }
          {
            int row = 32 + q32;
            int slot = (kt * 4 + kc * 2 + hi) ^ (row & 7);
            bf16x8 vf = *(const bf16x8*)&VB[row * 64 + slot * 8];
            o1 = MFMA32(af.v, vf, o1);
          }
          lacc = MFMA32(af.v, ones, lacc);   // row-sum on the MFMA pipe
        }
      }
      __builtin_amdgcn_s_setprio(0);
      __syncthreads();
      mvCur = mvNext;
    }
  }

#pragma unroll
  for (int i = 0; i < 16; ++i) {
    int rq = (i & 3) + 8 * (i >> 2) + 4 * hi;
    float inv = __builtin_amdgcn_rcpf(lacc[i]);
    int row = q0 + rq;
    O[(bS + row) * DM_ + h * DH_ + q32] = f2bf(o0[i] * inv);
    O[(bS + row) * DM_ + h * DH_ + 32 + q32] = f2bf(o1[i] * inv);
  }
}

// ---------------- host ----------------
extern "C" void kernel_launch(void* const* d_in, const int* in_sizes, int n_in,
                              void* d_out, int out_size, void* d_ws, size_t ws_size,
                              hipStream_t stream) {
  const float* x     = (const float*)d_in[0];
  const float* eo    = (const float*)d_in[1];
  const int*   tmask = (const int*)d_in[2];
  const float* m1_wq = (const float*)d_in[4];  const float* m1_bq = (const float*)d_in[5];
  const float* m1_wk = (const float*)d_in[6];  const float* m1_bk = (const float*)d_in[7];
  const float* m1_wv = (const float*)d_in[8];  const float* m1_bv = (const float*)d_in[9];
  const float* m1_w2 = (const float*)d_in[10]; const float* m1_b2 = (const float*)d_in[11];
  const float* m1_g  = (const float*)d_in[12]; const float* m1_b  = (const float*)d_in[13];
  const float* m2_wq = (const float*)d_in[14]; const float* m2_bq = (const float*)d_in[15];
  const float* m2_wk = (const float*)d_in[16]; const float* m2_bk = (const float*)d_in[17];
  const float* m2_wv = (const float*)d_in[18]; const float* m2_bv = (const float*)d_in[19];
  const float* m2_w2 = (const float*)d_in[20]; const float* m2_b2 = (const float*)d_in[21];
  const float* m2_g  = (const float*)d_in[22]; const float* m2_b  = (const float*)d_in[23];
  const float* ln1_g = (const float*)d_in[24]; const float* ln1_b = (const float*)d_in[25];
  const float* ln2_g = (const float*)d_in[26]; const float* ln2_b = (const float*)d_in[27];
  const float* ln3_g = (const float*)d_in[28]; const float* ln3_b = (const float*)d_in[29];
  const float* f_w1  = (const float*)d_in[30]; const float* f_b1  = (const float*)d_in[31];
  const float* f_w2  = (const float*)d_in[32]; const float* f_b2  = (const float*)d_in[33];

  char* ws = (char*)d_ws;
  size_t off = 0;
  auto alloc = [&](size_t bytes) -> void* {
    void* p = ws + off;
    off += (bytes + 255) & ~(size_t)255;
    return p;
  };
  unsigned short* wt[10];
  for (int i = 0; i < 10; ++i) wt[i] = (unsigned short*)alloc(131072 * 2);
  unsigned short* xb  = (unsigned short*)alloc((size_t)M_ * DIN_ * 2);
  unsigned short* eb  = (unsigned short*)alloc((size_t)M_ * DIN_ * 2);
  unsigned short* Qb  = (unsigned short*)alloc((size_t)M_ * DM_ * 2);
  unsigned short* Kb  = (unsigned short*)alloc((size_t)M_ * DM_ * 2);
  unsigned short* AOb = (unsigned short*)alloc((size_t)M_ * DM_ * 2);
  float*          X1  = (float*)alloc((size_t)M_ * DIN_ * 4);
  unsigned short* X1b = (unsigned short*)alloc((size_t)M_ * DIN_ * 2);
  float*          X2  = (float*)alloc((size_t)M_ * DIN_ * 4);
  unsigned short* X2b = (unsigned short*)alloc((size_t)M_ * DIN_ * 2);
  unsigned short* VtA = (unsigned short*)alloc((size_t)M_ * DM_ * 2);  // [B][512][2048]
  unsigned short* VtB = (unsigned short*)alloc((size_t)M_ * DM_ * 2);
  unsigned short* Hb  = Qb;                      // dead by FFN stage

  int n4 = M_ * DIN_ / 4;
  cast_bf16_kernel<<<dim3(n4 / 256, 2), 256, 0, stream>>>(x, eo, xb, eb, n4);

  WtDesc wd;
  const float* srcs[10] = {m1_wq, m1_wk, m1_wv, m1_w2, m2_wq, m2_wk, m2_wv, m2_w2, f_w1, f_w2};
  int kss[10]           = {8,     8,     8,     9,     8,     8,     8,     9,     8,    9};
  for (int i = 0; i < 10; ++i) { wd.src[i] = srcs[i]; wd.dst[i] = wt[i]; wd.ks[i] = kss[i]; }
  prep_w_kernel<<<dim3(512, 10), 256, 0, stream>>>(wd);

  const int FG = (S_ / 128) * H_ * B_;   // 512 flat blocks, XCD-grouped in-kernel
  const float QSCALE = 0.125f * 1.44269504088896f;   // 1/sqrt(DH) * log2(e)

  // ---- stage A: masked self-attention (V written transposed by GEMM) ----
  gemm_tiled_kernel<256, false><<<dim3(M_ / 128, 12), 256, 0, stream>>>(
      xb, xb, xb, wt[0], wt[1], wt[2], m1_bq, m1_bk, m1_bv, Qb, Kb, VtA, QSCALE, 2);
  flash_kernel<true><<<FG, 256, 0, stream>>>(Qb, Kb, VtA, tmask, AOb);
  gemm_ln_kernel<2><<<M_ / 16, 256, 0, stream>>>(AOb, wt[3], m1_b2, x,
                                                 m1_g, m1_b, ln1_g, ln1_b, X1, X1b);
  // ---- stage B: cross-attention; Q from X1b, K/V from eb (V transposed) ----
  gemm_tiled_kernel<256, false><<<dim3(M_ / 128, 12), 256, 0, stream>>>(
      X1b, eb, eb, wt[4], wt[5], wt[6], m2_bq, m2_bk, m2_bv, Qb, Kb, VtB, QSCALE, 2);
  flash_kernel<false><<<FG, 256, 0, stream>>>(Qb, Kb, VtB, nullptr, AOb);
  gemm_ln_kernel<2><<<M_ / 16, 256, 0, stream>>>(AOb, wt[7], m2_b2, X1,
                                                 m2_g, m2_b, ln2_g, ln2_b, X2, X2b);
  // ---- stage C: FFN ----
  gemm_tiled_kernel<256, true><<<dim3(M_ / 128, 4), 256, 0, stream>>>(
      X2b, X2b, X2b, wt[8], wt[8], wt[8], f_b1, f_b1, f_b1, Hb, Hb, Hb, 1.f, -1);
  gemm_ln_kernel<1><<<M_ / 16, 256, 0, stream>>>(Hb, wt[9], f_b2, X2,
                                                 ln3_g, ln3_b, nullptr, nullptr,
                                                 (float*)d_out, nullptr);
}

// Round 18
// 192.234 us; speedup vs baseline: 1.2520x; 1.0236x over previous
//
#include <hip/hip_runtime.h>
#include <hip/hip_bf16.h>

#define B_ 4
#define S_ 2048
#define DIN_ 256
#define DM_ 512
#define H_ 8
#define DH_ 64
#define M_ (B_*S_)

typedef short bf16x8 __attribute__((ext_vector_type(8)));
typedef float f32x4 __attribute__((ext_vector_type(4)));
typedef float f32x16 __attribute__((ext_vector_type(16)));
typedef int v2i __attribute__((ext_vector_type(2)));
typedef unsigned int u32;
typedef unsigned long long u64;

#define MFMA16(a,b,c) __builtin_amdgcn_mfma_f32_16x16x32_bf16((a),(b),(c),0,0,0)
#define MFMA32(a,b,c) __builtin_amdgcn_mfma_f32_32x32x16_bf16((a),(b),(c),0,0,0)

__device__ __forceinline__ unsigned short f2bf(float f) {
  union { float f; unsigned u; } v; v.f = f;
  unsigned r = v.u + 0x7fffu + ((v.u >> 16) & 1u);
  return (unsigned short)(r >> 16);
}
__device__ __forceinline__ f32x4 f32x4_zero() { f32x4 v = {0.f,0.f,0.f,0.f}; return v; }
__device__ __forceinline__ f32x16 f32x16_zero() {
  f32x16 v;
#pragma unroll
  for (int i = 0; i < 16; ++i) v[i] = 0.f;
  return v;
}
__device__ __forceinline__ u32 cvtpk_bf16(float lo, float hi) {
  u32 r; asm("v_cvt_pk_bf16_f32 %0, %1, %2" : "=v"(r) : "v"(lo), "v"(hi)); return r;
}
__device__ __forceinline__ float exp2_asm(float x) {
  float r; asm("v_exp_f32 %0, %1" : "=v"(r) : "v"(x)); return r;
}
__device__ __forceinline__ float max3f(float a, float b, float c) {
  return fmaxf(fmaxf(a, b), c);   // clang fuses to v_max3_f32
}
__device__ __forceinline__ void gload_lds16(const void* g, void* l) {
  __builtin_amdgcn_global_load_lds((const __attribute__((address_space(1))) unsigned int*)g,
                                   (__attribute__((address_space(3))) unsigned int*)l,
                                   16, 0, 0);
}

// ---------------- fp32 -> bf16 cast (two tensors, one launch) ----------------
__global__ void cast_bf16_kernel(const float* __restrict__ inA,
                                 const float* __restrict__ inB,
                                 unsigned short* __restrict__ outA,
                                 unsigned short* __restrict__ outB, int n4) {
  const float* in = blockIdx.y ? inB : inA;
  unsigned short* out = blockIdx.y ? outB : outA;
  int i = blockIdx.x * blockDim.x + threadIdx.x;
  if (i < n4) {
    float4 v = ((const float4*)in)[i];
    ushort4 o;
    o.x = f2bf(v.x); o.y = f2bf(v.y); o.z = f2bf(v.z); o.w = f2bf(v.w);
    ((ushort4*)out)[i] = o;
  }
}

// ---------------- weight prep v2: W[K][N] fp32 -> Wt[N][K] bf16 --------------
// 64x64 tile transpose through padded LDS: coalesced float4 reads, coalesced
// bf16x8 writes. 32 tiles per matrix, 10 matrices -> grid (32, 10).
struct WtDesc {
  const float* src[10];
  unsigned short* dst[10];
  int ks[10];
};
__global__ __launch_bounds__(256) void prep_w_kernel(WtDesc d) {
  __shared__ float T[64][65];
  const int m = blockIdx.y;
  const int ks = d.ks[m];
  const int K = 1 << ks;                  // inner dim of Wt (rows of src)
  const int N = 131072 >> ks;             // cols of src
  const int nk = K >> 6;
  const int kt = blockIdx.x % nk, nt = blockIdx.x / nk;
  const int k0 = kt * 64, n0 = nt * 64;
  const int tid = threadIdx.x;
  const float* src = d.src[m];
  unsigned short* dst = d.dst[m];

  // read: 4 passes x (16 k-rows x 64 n-cols); 16 lanes cover 256B contiguous
  const int rk = tid >> 4, rn = (tid & 15) * 4;
#pragma unroll
  for (int p = 0; p < 4; ++p) {
    int kk = p * 16 + rk;
    float4 v = *(const float4*)&src[(size_t)(k0 + kk) * N + n0 + rn];
    T[kk][rn] = v.x; T[kk][rn + 1] = v.y; T[kk][rn + 2] = v.z; T[kk][rn + 3] = v.w;
  }
  __syncthreads();

  // write: 2 passes x (32 n-rows x 64 k); 8 lanes cover 128B contiguous
  const int wn = tid >> 3, wk = (tid & 7) * 8;
#pragma unroll
  for (int p = 0; p < 2; ++p) {
    int nn = p * 32 + wn;
    bf16x8 o;
#pragma unroll
    for (int j = 0; j < 8; ++j) o[j] = (short)f2bf(T[wk + j][nn]);
    *(bf16x8*)&dst[(size_t)(n0 + nn) * K + k0 + wk] = o;
  }
}

// ---------------- tiled GEMM (m97 structure): 128x128 tile, BK=32 ----------------
// Per-sel A pointer so independent GEMMs share one launch. sel == trsel
// writes its output in transposed Vt layout [B][DM][S] (fused V-transpose).
// K-loop parity-unrolled: compile-time LDS buffer index.
template<int K, bool RELU>
__global__ __launch_bounds__(256) void gemm_tiled_kernel(
    const unsigned short* __restrict__ A0, const unsigned short* __restrict__ A1,
    const unsigned short* __restrict__ A2,
    const unsigned short* __restrict__ W0, const unsigned short* __restrict__ W1,
    const unsigned short* __restrict__ W2,
    const float* __restrict__ b0, const float* __restrict__ b1, const float* __restrict__ b2,
    unsigned short* __restrict__ o0, unsigned short* __restrict__ o1,
    unsigned short* __restrict__ o2, float scale0, int trsel) {
  const int sel = blockIdx.y >> 2;
  const unsigned short* A = sel == 0 ? A0 : (sel == 1 ? A1 : A2);
  const unsigned short* Wt = sel == 0 ? W0 : (sel == 1 ? W1 : W2);
  const float* bias = sel == 0 ? b0 : (sel == 1 ? b1 : b2);
  unsigned short* out = sel == 0 ? o0 : (sel == 1 ? o1 : o2);
  const float scale = sel == 0 ? scale0 : 1.f;

  const int tid = threadIdx.x;
  const int w = tid >> 6, l = tid & 63;
  const int lr = l & 15, lg = l >> 4;
  const int wr = w >> 1, wc = w & 1;
  const int r0 = blockIdx.x * 128;
  const int c0 = (blockIdx.y & 3) * 128;

  __shared__ __align__(16) unsigned short As[2][128 * 32];
  __shared__ __align__(16) unsigned short Bs[2][128 * 32];

  f32x4 acc[4][4];
#pragma unroll
  for (int m = 0; m < 4; ++m)
#pragma unroll
    for (int n = 0; n < 4; ++n) acc[m][n] = f32x4_zero();

  auto stage = [&](int buf, int k0) {
#pragma unroll
    for (int i = 0; i < 2; ++i) {
      int c = w * 128 + i * 64 + l;      // 512 chunks of 16B each for A and B
      int row = c >> 2, sl = c & 3;
      gload_lds16(A + (size_t)(r0 + row) * K + k0 + sl * 8,
                  &As[buf][(w * 128 + i * 64) * 8]);
      gload_lds16(Wt + (size_t)(c0 + row) * K + k0 + sl * 8,
                  &Bs[buf][(w * 128 + i * 64) * 8]);
    }
  };

  stage(0, 0);
  __syncthreads();

  const int NT = K / 32;                 // 8 or 16, even
  for (int tt = 0; tt < NT; tt += 2) {
#pragma unroll
    for (int u = 0; u < 2; ++u) {
      const int t = tt + u;
      if (t + 1 < NT) stage(u ^ 1, (t + 1) * 32);
      const unsigned short* AB = &As[u][0];
      const unsigned short* BB = &Bs[u][0];
      bf16x8 af[4], bf[4];
#pragma unroll
      for (int m = 0; m < 4; ++m)
        af[m] = *(const bf16x8*)&AB[(wr * 64 + m * 16 + lr) * 32 + lg * 8];
#pragma unroll
      for (int n = 0; n < 4; ++n)
        bf[n] = *(const bf16x8*)&BB[(wc * 64 + n * 16 + lr) * 32 + lg * 8];
#pragma unroll
      for (int m = 0; m < 4; ++m)
#pragma unroll
        for (int n = 0; n < 4; ++n)
          acc[m][n] = MFMA16(af[m], bf[n], acc[m][n]);
      __syncthreads();
    }
  }

  if (sel != trsel) {
#pragma unroll
    for (int n = 0; n < 4; ++n) {
      int col = c0 + wc * 64 + n * 16 + lr;
      float bv = bias[col];
#pragma unroll
      for (int m = 0; m < 4; ++m) {
#pragma unroll
        for (int r = 0; r < 4; ++r) {
          int row = r0 + wr * 64 + m * 16 + lg * 4 + r;
          float v = (acc[m][n][r] + bv) * scale;
          if (RELU) v = fmaxf(v, 0.f);
          out[(size_t)row * DM_ + col] = f2bf(v);
        }
      }
    }
  } else {
    // transposed write: out = Vt [B][DM][S]; block lies in one batch
    const int bb = r0 / S_;
    const int sbase = r0 - bb * S_ + wr * 64 + lg * 4;
#pragma unroll
    for (int n = 0; n < 4; ++n) {
      int col = c0 + wc * 64 + n * 16 + lr;
      float bv = bias[col];
#pragma unroll
      for (int m = 0; m < 4; ++m) {
        ushort4 o;
#pragma unroll
        for (int r = 0; r < 4; ++r) {
          float v = acc[m][n][r] + bv;
          ((unsigned short*)&o)[r] = f2bf(v);
        }
        *(ushort4*)&out[((size_t)bb * DM_ + col) * S_ + sbase + m * 16] = o;
      }
    }
  }
}

// ---------------- GEMM + bias + residual + LayerNorm epilogue (16-row, BK=64) --
// Block 256 = 4 waves; wave w owns cols [w*64, w*64+64). 8 k-iterations of
// BK=64 (8 MFMA/wave per barrier), parity-unrolled. 128B LDS rows XOR-swizzled.
template<int NLN>
__global__ __launch_bounds__(256) void gemm_ln_kernel(
    const unsigned short* __restrict__ A,
    const unsigned short* __restrict__ Wt,
    const float* __restrict__ bias,
    const float* __restrict__ res,
    const float* __restrict__ gA, const float* __restrict__ bA,
    const float* __restrict__ gB, const float* __restrict__ bB,
    float* __restrict__ outF,
    unsigned short* __restrict__ outB) {
  const int tid = threadIdx.x;
  const int w = tid >> 6, l = tid & 63;
  const int lr = l & 15, lg = l >> 4;
  const int r0 = blockIdx.x * 16;

  __shared__ __align__(16) unsigned short Bs[2][256 * 64];  // 32KB each
  __shared__ __align__(16) unsigned short As[2][16 * 64];   // 2KB each
  __shared__ float ex[16][4][2];

  f32x4 acc[4];
#pragma unroll
  for (int n = 0; n < 4; ++n) acc[n] = f32x4_zero();

  auto stage = [&](int buf, int k0) {
#pragma unroll
    for (int p = 0; p < 8; ++p) {        // B: 2048 chunks (256 rows x 8 slots)
      int c = (w * 8 + p) * 64 + l;
      int row = c >> 3, sl = c & 7;
      gload_lds16(Wt + (size_t)row * 512 + k0 + ((sl ^ (row & 7)) * 8),
                  &Bs[buf][(w * 8 + p) * 64 * 8]);
    }
    if (w == 0) {                         // A: 128 chunks (16 rows x 8 slots)
#pragma unroll
      for (int p = 0; p < 2; ++p) {
        int c = p * 64 + l;
        int row = c >> 3, sl = c & 7;
        gload_lds16(A + (size_t)(r0 + row) * 512 + k0 + ((sl ^ (row & 7)) * 8),
                    &As[buf][p * 64 * 8]);
      }
    }
  };

  stage(0, 0);
  __syncthreads();

  for (int tt = 0; tt < 8; tt += 2) {
#pragma unroll
    for (int u = 0; u < 2; ++u) {
      const int t = tt + u;
      if (t + 1 < 8) stage(u ^ 1, (t + 1) * 64);
      const unsigned short* BB = &Bs[u][0];
      const unsigned short* AB = &As[u][0];
#pragma unroll
      for (int kk = 0; kk < 2; ++kk) {
        bf16x8 a = *(const bf16x8*)&AB[lr * 64 + (((kk * 4 + lg) ^ (lr & 7)) * 8)];
#pragma unroll
        for (int n = 0; n < 4; ++n) {
          int row = w * 64 + n * 16 + lr;
          bf16x8 b = *(const bf16x8*)&BB[row * 64 + (((kk * 4 + lg) ^ (row & 7)) * 8)];
          acc[n] = MFMA16(a, b, acc[n]);
        }
      }
      __syncthreads();
    }
  }

  f32x4 rv[4];
#pragma unroll
  for (int n = 0; n < 4; ++n) {
    int col = w * 64 + n * 16 + lr;
    float bv = bias[col];
#pragma unroll
    for (int r = 0; r < 4; ++r) {
      int row = r0 + lg * 4 + r;
      float rr = res[(size_t)row * 256 + col];
      rv[n][r] = rr;
      acc[n][r] += bv + rr;
    }
  }

  auto ln_stats = [&](float* mu, float* rs) {
    float s1[4], s2[4];
#pragma unroll
    for (int r = 0; r < 4; ++r) {
      float a1 = 0.f, a2 = 0.f;
#pragma unroll
      for (int n = 0; n < 4; ++n) { float v = acc[n][r]; a1 += v; a2 += v * v; }
#pragma unroll
      for (int off = 1; off < 16; off <<= 1) {
        a1 += __shfl_xor(a1, off);
        a2 += __shfl_xor(a2, off);
      }
      s1[r] = a1; s2[r] = a2;
    }
    if (lr == 0) {
#pragma unroll
      for (int r = 0; r < 4; ++r) {
        ex[lg * 4 + r][w][0] = s1[r];
        ex[lg * 4 + r][w][1] = s2[r];
      }
    }
    __syncthreads();
#pragma unroll
    for (int r = 0; r < 4; ++r) {
      int row = lg * 4 + r;
      float t1 = ex[row][0][0] + ex[row][1][0] + ex[row][2][0] + ex[row][3][0];
      float t2 = ex[row][0][1] + ex[row][1][1] + ex[row][2][1] + ex[row][3][1];
      float m = t1 * (1.f / 256.f);
      float var = t2 * (1.f / 256.f) - m * m;
      mu[r] = m;
      rs[r] = rsqrtf(var + 1e-6f);
    }
  };

  float mu[4], rs[4];
  ln_stats(mu, rs);

  if constexpr (NLN == 2) {
#pragma unroll
    for (int n = 0; n < 4; ++n) {
      int col = w * 64 + n * 16 + lr;
      float g = gA[col], bb = bA[col];
#pragma unroll
      for (int r = 0; r < 4; ++r) {
        float t1 = (acc[n][r] - mu[r]) * rs[r] * g + bb;
        acc[n][r] = rv[n][r] + t1;
      }
    }
    __syncthreads();
    float mu2[4], rs2[4];
    ln_stats(mu2, rs2);
#pragma unroll
    for (int n = 0; n < 4; ++n) {
      int col = w * 64 + n * 16 + lr;
      float g = gB[col], bb = bB[col];
#pragma unroll
      for (int r = 0; r < 4; ++r) {
        int row = r0 + lg * 4 + r;
        float o = (acc[n][r] - mu2[r]) * rs2[r] * g + bb;
        outF[(size_t)row * 256 + col] = o;
        outB[(size_t)row * 256 + col] = f2bf(o);
      }
    }
  } else {
#pragma unroll
    for (int n = 0; n < 4; ++n) {
      int col = w * 64 + n * 16 + lr;
      float g = gA[col], bb = bA[col];
#pragma unroll
      for (int r = 0; r < 4; ++r) {
        int row = r0 + lg * 4 + r;
        float o = (acc[n][r] - mu[r]) * rs[r] * g + bb;
        outF[(size_t)row * 256 + col] = o;
      }
    }
  }
}

// ---------------- Flash attention v10 (r15, measured best: 58.7us) ----------
// Block 256 = 4 waves each owning 32 q-rows, shared double-buffered 64-key
// K/V tiles (32KB LDS). Flat grid 512 with XCD-grouped mapping. Tile loop
// parity-unrolled. Mask via rank-1 MFMA bias; rowsum on the MFMA pipe.
template<bool MASKED>
__global__ __launch_bounds__(256) void flash_kernel(
    const unsigned short* __restrict__ Q,
    const unsigned short* __restrict__ Kg,
    const unsigned short* __restrict__ Vt,
    const int* __restrict__ mask,
    unsigned short* __restrict__ O) {
  __shared__ __align__(16) unsigned short lds[2][2][64 * 64];
  const int tid = threadIdx.x;
  const int w = tid >> 6, l = tid & 63;
  const int q32 = l & 31, hi = l >> 5;
  const int id = blockIdx.x;
  const int g = (id & 7) * 64 + (id >> 3);
  const int bh = g >> 4, xblk = g & 15;
  const int b = bh >> 3, h = bh & 7;
  const size_t bS = (size_t)b * S_;
  const int q0 = xblk * 128 + w * 32;

  bf16x8 qf[4];
  {
    const unsigned short* qp = Q + (bS + q0 + q32) * DM_ + h * DH_;
#pragma unroll
    for (int c = 0; c < 4; ++c) qf[c] = *(const bf16x8*)(qp + c * 16 + hi * 8);
  }
  bf16x8 ones;
#pragma unroll
  for (int j = 0; j < 8; ++j) ones[j] = (short)0x3F80;   // bf16 1.0

  f32x16 o0 = f32x16_zero(), o1 = f32x16_zero(), lacc = f32x16_zero();
  float m = -1e30f;

  auto stage = [&](int buf, int kv0) {
#pragma unroll
    for (int p = 0; p < 2; ++p) {
      int i = w * 2 + p;                 // 0..7
      int row = i * 8 + (l >> 3);
      int slot = l & 7;
      gload_lds16(Kg + (bS + kv0 + row) * DM_ + h * DH_ + ((slot ^ (row & 7)) * 8),
                  &lds[buf][0][i * 8 * 64]);
      gload_lds16(Vt + ((size_t)b * DM_ + h * DH_ + row) * S_ + kv0 + ((slot ^ (row & 7)) * 8),
                  &lds[buf][1][i * 8 * 64]);
    }
  };

  stage(0, 0);
  int mvCur = 1;
  if (MASKED) mvCur = mask[bS + l];
  __syncthreads();

  const int NT = S_ / 64;   // 32, even
  for (int tt = 0; tt < NT; tt += 2) {
#pragma unroll
    for (int u = 0; u < 2; ++u) {        // u = buffer index (compile-time)
      const int t = tt + u;
      int mvNext = 1;
      if (t + 1 < NT) {
        stage(u ^ 1, (t + 1) * 64);
        if (MASKED) mvNext = mask[bS + (t + 1) * 64 + l];
      }
      u64 bits = 0;
      if (MASKED) bits = __ballot(mvCur != 0);

      const unsigned short* KB = &lds[u][0][0];
      const unsigned short* VB = &lds[u][1][0];

      f32x16 sc[2];
      __builtin_amdgcn_s_setprio(1);
#pragma unroll
      for (int kt = 0; kt < 2; ++kt) {
        f32x16 s = f32x16_zero();
#pragma unroll
        for (int c = 0; c < 4; ++c) {
          int row = kt * 32 + q32;
          int slot = (c * 2 + hi) ^ (row & 7);
          bf16x8 kf = *(const bf16x8*)&KB[row * 64 + slot * 8];
          s = MFMA32(kf, qf[c], s);
        }
        if (MASKED) {
          u32 valid = (u32)(bits >> (kt * 32 + q32)) & 1u;
          u32 mfw = valid ? 0u : 0xC080C080u;   // bf16 -4.0 pair; 16 k-slots -> -64
          union { u32 u[4]; bf16x8 v; } mf;
          mf.u[0] = mfw; mf.u[1] = mfw; mf.u[2] = mfw; mf.u[3] = mfw;
          s = MFMA32(mf.v, ones, s);
        }
        sc[kt] = s;
      }
      __builtin_amdgcn_s_setprio(0);

      float tm;
      {
        float r01;
#pragma unroll
        for (int kt = 0; kt < 2; ++kt) {
          float m0 = max3f(sc[kt][0], sc[kt][1], sc[kt][2]);
          float m1 = max3f(sc[kt][3], sc[kt][4], sc[kt][5]);
          float m2 = max3f(sc[kt][6], sc[kt][7], sc[kt][8]);
          float m3 = max3f(sc[kt][9], sc[kt][10], sc[kt][11]);
          float m4 = max3f(sc[kt][12], sc[kt][13], sc[kt][14]);
          float r = fmaxf(max3f(max3f(m0, m1, m2), m3, m4), sc[kt][15]);
          if (kt == 0) r01 = r; else r01 = fmaxf(r01, r);
        }
        tm = fmaxf(r01, __shfl_xor(r01, 32));
      }

      if (__any(tm > m + 11.5f)) {       // defer-max, THR = 11.5 bits
        float mn = fmaxf(m, tm);
        float fac = exp2_asm(m - mn);
        m = mn;
#pragma unroll
        for (int i = 0; i < 16; ++i) {
          int rq = (i & 3) + 8 * (i >> 2) + 4 * hi;
          float fr = __shfl(fac, rq);
          o0[i] *= fr;
          o1[i] *= fr;
          lacc[i] *= fr;
        }
      }

      float pv[2][16];
#pragma unroll
      for (int kt = 0; kt < 2; ++kt)
#pragma unroll
        for (int i = 0; i < 16; ++i) pv[kt][i] = exp2_asm(sc[kt][i] - m);

      u32 w8[2][8];
#pragma unroll
      for (int kt = 0; kt < 2; ++kt)
#pragma unroll
        for (int j = 0; j < 8; ++j)
          w8[kt][j] = cvtpk_bf16(pv[kt][2 * j], pv[kt][2 * j + 1]);

      __builtin_amdgcn_s_setprio(1);
#pragma unroll
      for (int kt = 0; kt < 2; ++kt) {
#pragma unroll
        for (int kc = 0; kc < 2; ++kc) {
          v2i r0 = __builtin_amdgcn_permlane32_swap((int)w8[kt][4 * kc + 0],
                                                    (int)w8[kt][4 * kc + 2], false, false);
          v2i r1 = __builtin_amdgcn_permlane32_swap((int)w8[kt][4 * kc + 1],
                                                    (int)w8[kt][4 * kc + 3], false, false);
          union { u32 u[4]; bf16x8 v; } af;
          af.u[0] = (u32)r0.x; af.u[1] = (u32)r1.x; af.u[2] = (u32)r0.y; af.u[3] = (u32)r1.y;
          {
            int row = q32;
            int slot = (kt * 4 + kc * 2 + hi) ^ (row & 7);
            bf16x8 vf = *(const bf16x8*)&VB[row * 64 + slot * 8];
            o0 = MFMA32(af.v, vf, o0);
          }
          {
            int row = 32 + q32;
            int slot = (kt * 4 + kc * 2 + hi) ^ (row & 7);
            bf16x8 vf = *(const bf16x8*)&VB[row * 64 + slot * 8];
            o1 = MFMA32(af.v, vf, o1);
          }
          lacc = MFMA32(af.v, ones, lacc);   // row-sum on the MFMA pipe
        }
      }
      __builtin_amdgcn_s_setprio(0);
      __syncthreads();
      mvCur = mvNext;
    }
  }

#pragma unroll
  for (int i = 0; i < 16; ++i) {
    int rq = (i & 3) + 8 * (i >> 2) + 4 * hi;
    float inv = __builtin_amdgcn_rcpf(lacc[i]);
    int row = q0 + rq;
    O[(bS + row) * DM_ + h * DH_ + q32] = f2bf(o0[i] * inv);
    O[(bS + row) * DM_ + h * DH_ + 32 + q32] = f2bf(o1[i] * inv);
  }
}

// ---------------- host ----------------
extern "C" void kernel_launch(void* const* d_in, const int* in_sizes, int n_in,
                              void* d_out, int out_size, void* d_ws, size_t ws_size,
                              hipStream_t stream) {
  const float* x     = (const float*)d_in[0];
  const float* eo    = (const float*)d_in[1];
  const int*   tmask = (const int*)d_in[2];
  const float* m1_wq = (const float*)d_in[4];  const float* m1_bq = (const float*)d_in[5];
  const float* m1_wk = (const float*)d_in[6];  const float* m1_bk = (const float*)d_in[7];
  const float* m1_wv = (const float*)d_in[8];  const float* m1_bv = (const float*)d_in[9];
  const float* m1_w2 = (const float*)d_in[10]; const float* m1_b2 = (const float*)d_in[11];
  const float* m1_g  = (const float*)d_in[12]; const float* m1_b  = (const float*)d_in[13];
  const float* m2_wq = (const float*)d_in[14]; const float* m2_bq = (const float*)d_in[15];
  const float* m2_wk = (const float*)d_in[16]; const float* m2_bk = (const float*)d_in[17];
  const float* m2_wv = (const float*)d_in[18]; const float* m2_bv = (const float*)d_in[19];
  const float* m2_w2 = (const float*)d_in[20]; const float* m2_b2 = (const float*)d_in[21];
  const float* m2_g  = (const float*)d_in[22]; const float* m2_b  = (const float*)d_in[23];
  const float* ln1_g = (const float*)d_in[24]; const float* ln1_b = (const float*)d_in[25];
  const float* ln2_g = (const float*)d_in[26]; const float* ln2_b = (const float*)d_in[27];
  const float* ln3_g = (const float*)d_in[28]; const float* ln3_b = (const float*)d_in[29];
  const float* f_w1  = (const float*)d_in[30]; const float* f_b1  = (const float*)d_in[31];
  const float* f_w2  = (const float*)d_in[32]; const float* f_b2  = (const float*)d_in[33];

  char* ws = (char*)d_ws;
  size_t off = 0;
  auto alloc = [&](size_t bytes) -> void* {
    void* p = ws + off;
    off += (bytes + 255) & ~(size_t)255;
    return p;
  };
  unsigned short* wt[10];
  for (int i = 0; i < 10; ++i) wt[i] = (unsigned short*)alloc(131072 * 2);
  unsigned short* xb  = (unsigned short*)alloc((size_t)M_ * DIN_ * 2);
  unsigned short* eb  = (unsigned short*)alloc((size_t)M_ * DIN_ * 2);
  unsigned short* Qb  = (unsigned short*)alloc((size_t)M_ * DM_ * 2);
  unsigned short* Kb  = (unsigned short*)alloc((size_t)M_ * DM_ * 2);
  unsigned short* AOb = (unsigned short*)alloc((size_t)M_ * DM_ * 2);
  float*          X1  = (float*)alloc((size_t)M_ * DIN_ * 4);
  unsigned short* X1b = (unsigned short*)alloc((size_t)M_ * DIN_ * 2);
  float*          X2  = (float*)alloc((size_t)M_ * DIN_ * 4);
  unsigned short* X2b = (unsigned short*)alloc((size_t)M_ * DIN_ * 2);
  unsigned short* VtA = (unsigned short*)alloc((size_t)M_ * DM_ * 2);  // [B][512][2048]
  unsigned short* VtB = (unsigned short*)alloc((size_t)M_ * DM_ * 2);
  unsigned short* Hb  = Qb;                      // dead by FFN stage

  int n4 = M_ * DIN_ / 4;
  cast_bf16_kernel<<<dim3(n4 / 256, 2), 256, 0, stream>>>(x, eo, xb, eb, n4);

  WtDesc wd;
  const float* srcs[10] = {m1_wq, m1_wk, m1_wv, m1_w2, m2_wq, m2_wk, m2_wv, m2_w2, f_w1, f_w2};
  int kss[10]           = {8,     8,     8,     9,     8,     8,     8,     9,     8,    9};
  for (int i = 0; i < 10; ++i) { wd.src[i] = srcs[i]; wd.dst[i] = wt[i]; wd.ks[i] = kss[i]; }
  prep_w_kernel<<<dim3(32, 10), 256, 0, stream>>>(wd);

  const int FG = (S_ / 128) * H_ * B_;   // 512 flat blocks, XCD-grouped in-kernel
  const float QSCALE = 0.125f * 1.44269504088896f;   // 1/sqrt(DH) * log2(e)

  // ---- stage A: masked self-attention (V written transposed by GEMM) ----
  gemm_tiled_kernel<256, false><<<dim3(M_ / 128, 12), 256, 0, stream>>>(
      xb, xb, xb, wt[0], wt[1], wt[2], m1_bq, m1_bk, m1_bv, Qb, Kb, VtA, QSCALE, 2);
  flash_kernel<true><<<FG, 256, 0, stream>>>(Qb, Kb, VtA, tmask, AOb);
  gemm_ln_kernel<2><<<M_ / 16, 256, 0, stream>>>(AOb, wt[3], m1_b2, x,
                                                 m1_g, m1_b, ln1_g, ln1_b, X1, X1b);
  // ---- stage B: cross-attention; Q from X1b, K/V from eb (V transposed) ----
  gemm_tiled_kernel<256, false><<<dim3(M_ / 128, 12), 256, 0, stream>>>(
      X1b, eb, eb, wt[4], wt[5], wt[6], m2_bq, m2_bk, m2_bv, Qb, Kb, VtB, QSCALE, 2);
  flash_kernel<false><<<FG, 256, 0, stream>>>(Qb, Kb, VtB, nullptr, AOb);
  gemm_ln_kernel<2><<<M_ / 16, 256, 0, stream>>>(AOb, wt[7], m2_b2, X1,
                                                 m2_g, m2_b, ln2_g, ln2_b, X2, X2b);
  // ---- stage C: FFN ----
  gemm_tiled_kernel<256, true><<<dim3(M_ / 128, 4), 256, 0, stream>>>(
      X2b, X2b, X2b, wt[8], wt[8], wt[8], f_b1, f_b1, f_b1, Hb, Hb, Hb, 1.f, -1);
  gemm_ln_kernel<1><<<M_ / 16, 256, 0, stream>>>(Hb, wt[9], f_b2, X2,
                                                 ln3_g, ln3_b, nullptr, nullptr,
                                                 (float*)d_out, nullptr);
}

// Round 19
// 189.897 us; speedup vs baseline: 1.2675x; 1.0123x over previous
//
#include <hip/hip_runtime.h>
#include <hip/hip_bf16.h>

#define B_ 4
#define S_ 2048
#define DIN_ 256
#define DM_ 512
#define H_ 8
#define DH_ 64
#define M_ (B_*S_)

typedef short bf16x8 __attribute__((ext_vector_type(8)));
typedef float f32x4 __attribute__((ext_vector_type(4)));
typedef float f32x16 __attribute__((ext_vector_type(16)));
typedef int v2i __attribute__((ext_vector_type(2)));
typedef unsigned int u32;
typedef unsigned long long u64;

#define MFMA16(a,b,c) __builtin_amdgcn_mfma_f32_16x16x32_bf16((a),(b),(c),0,0,0)
#define MFMA32(a,b,c) __builtin_amdgcn_mfma_f32_32x32x16_bf16((a),(b),(c),0,0,0)

__device__ __forceinline__ unsigned short f2bf(float f) {
  union { float f; unsigned u; } v; v.f = f;
  unsigned r = v.u + 0x7fffu + ((v.u >> 16) & 1u);
  return (unsigned short)(r >> 16);
}
__device__ __forceinline__ float bf2f(unsigned short b) {
  union { unsigned u; float f; } v; v.u = (unsigned)b << 16; return v.f;
}
__device__ __forceinline__ f32x4 f32x4_zero() { f32x4 v = {0.f,0.f,0.f,0.f}; return v; }
__device__ __forceinline__ f32x16 f32x16_zero() {
  f32x16 v;
#pragma unroll
  for (int i = 0; i < 16; ++i) v[i] = 0.f;
  return v;
}
__device__ __forceinline__ u32 cvtpk_bf16(float lo, float hi) {
  u32 r; asm("v_cvt_pk_bf16_f32 %0, %1, %2" : "=v"(r) : "v"(lo), "v"(hi)); return r;
}
__device__ __forceinline__ float exp2_asm(float x) {
  float r; asm("v_exp_f32 %0, %1" : "=v"(r) : "v"(x)); return r;
}
__device__ __forceinline__ float max3f(float a, float b, float c) {
  return fmaxf(fmaxf(a, b), c);   // clang fuses to v_max3_f32
}
__device__ __forceinline__ void gload_lds16(const void* g, void* l) {
  __builtin_amdgcn_global_load_lds((const __attribute__((address_space(1))) unsigned int*)g,
                                   (__attribute__((address_space(3))) unsigned int*)l,
                                   16, 0, 0);
}

// ---------------- fp32 -> bf16 cast (two tensors, one launch) ----------------
__global__ void cast_bf16_kernel(const float* __restrict__ inA,
                                 const float* __restrict__ inB,
                                 unsigned short* __restrict__ outA,
                                 unsigned short* __restrict__ outB, int n4) {
  const float* in = blockIdx.y ? inB : inA;
  unsigned short* out = blockIdx.y ? outB : outA;
  int i = blockIdx.x * blockDim.x + threadIdx.x;
  if (i < n4) {
    float4 v = ((const float4*)in)[i];
    ushort4 o;
    o.x = f2bf(v.x); o.y = f2bf(v.y); o.z = f2bf(v.z); o.w = f2bf(v.w);
    ((ushort4*)out)[i] = o;
  }
}

// ---------------- weight prep v2: W[K][N] fp32 -> Wt[N][K] bf16 --------------
struct WtDesc {
  const float* src[10];
  unsigned short* dst[10];
  int ks[10];
};
__global__ __launch_bounds__(256) void prep_w_kernel(WtDesc d) {
  __shared__ float T[64][65];
  const int m = blockIdx.y;
  const int ks = d.ks[m];
  const int K = 1 << ks;                  // inner dim of Wt (rows of src)
  const int N = 131072 >> ks;             // cols of src
  const int nk = K >> 6;
  const int kt = blockIdx.x % nk, nt = blockIdx.x / nk;
  const int k0 = kt * 64, n0 = nt * 64;
  const int tid = threadIdx.x;
  const float* src = d.src[m];
  unsigned short* dst = d.dst[m];

  const int rk = tid >> 4, rn = (tid & 15) * 4;
#pragma unroll
  for (int p = 0; p < 4; ++p) {
    int kk = p * 16 + rk;
    float4 v = *(const float4*)&src[(size_t)(k0 + kk) * N + n0 + rn];
    T[kk][rn] = v.x; T[kk][rn + 1] = v.y; T[kk][rn + 2] = v.z; T[kk][rn + 3] = v.w;
  }
  __syncthreads();

  const int wn = tid >> 3, wk = (tid & 7) * 8;
#pragma unroll
  for (int p = 0; p < 2; ++p) {
    int nn = p * 32 + wn;
    bf16x8 o;
#pragma unroll
    for (int j = 0; j < 8; ++j) o[j] = (short)f2bf(T[wk + j][nn]);
    *(bf16x8*)&dst[(size_t)(n0 + nn) * K + k0 + wk] = o;
  }
}

// ---------------- tiled GEMM (m97 structure): 128x128 tile, BK=32 ----------------
template<int K, bool RELU>
__global__ __launch_bounds__(256) void gemm_tiled_kernel(
    const unsigned short* __restrict__ A0, const unsigned short* __restrict__ A1,
    const unsigned short* __restrict__ A2,
    const unsigned short* __restrict__ W0, const unsigned short* __restrict__ W1,
    const unsigned short* __restrict__ W2,
    const float* __restrict__ b0, const float* __restrict__ b1, const float* __restrict__ b2,
    unsigned short* __restrict__ o0, unsigned short* __restrict__ o1,
    unsigned short* __restrict__ o2, float scale0, int trsel) {
  const int sel = blockIdx.y >> 2;
  const unsigned short* A = sel == 0 ? A0 : (sel == 1 ? A1 : A2);
  const unsigned short* Wt = sel == 0 ? W0 : (sel == 1 ? W1 : W2);
  const float* bias = sel == 0 ? b0 : (sel == 1 ? b1 : b2);
  unsigned short* out = sel == 0 ? o0 : (sel == 1 ? o1 : o2);
  const float scale = sel == 0 ? scale0 : 1.f;

  const int tid = threadIdx.x;
  const int w = tid >> 6, l = tid & 63;
  const int lr = l & 15, lg = l >> 4;
  const int wr = w >> 1, wc = w & 1;
  const int r0 = blockIdx.x * 128;
  const int c0 = (blockIdx.y & 3) * 128;

  __shared__ __align__(16) unsigned short As[2][128 * 32];
  __shared__ __align__(16) unsigned short Bs[2][128 * 32];

  f32x4 acc[4][4];
#pragma unroll
  for (int m = 0; m < 4; ++m)
#pragma unroll
    for (int n = 0; n < 4; ++n) acc[m][n] = f32x4_zero();

  auto stage = [&](int buf, int k0) {
#pragma unroll
    for (int i = 0; i < 2; ++i) {
      int c = w * 128 + i * 64 + l;      // 512 chunks of 16B each for A and B
      int row = c >> 2, sl = c & 3;
      gload_lds16(A + (size_t)(r0 + row) * K + k0 + sl * 8,
                  &As[buf][(w * 128 + i * 64) * 8]);
      gload_lds16(Wt + (size_t)(c0 + row) * K + k0 + sl * 8,
                  &Bs[buf][(w * 128 + i * 64) * 8]);
    }
  };

  stage(0, 0);
  __syncthreads();

  const int NT = K / 32;                 // 8 or 16, even
  for (int tt = 0; tt < NT; tt += 2) {
#pragma unroll
    for (int u = 0; u < 2; ++u) {
      const int t = tt + u;
      if (t + 1 < NT) stage(u ^ 1, (t + 1) * 32);
      const unsigned short* AB = &As[u][0];
      const unsigned short* BB = &Bs[u][0];
      bf16x8 af[4], bf[4];
#pragma unroll
      for (int m = 0; m < 4; ++m)
        af[m] = *(const bf16x8*)&AB[(wr * 64 + m * 16 + lr) * 32 + lg * 8];
#pragma unroll
      for (int n = 0; n < 4; ++n)
        bf[n] = *(const bf16x8*)&BB[(wc * 64 + n * 16 + lr) * 32 + lg * 8];
#pragma unroll
      for (int m = 0; m < 4; ++m)
#pragma unroll
        for (int n = 0; n < 4; ++n)
          acc[m][n] = MFMA16(af[m], bf[n], acc[m][n]);
      __syncthreads();
    }
  }

  if (sel != trsel) {
#pragma unroll
    for (int n = 0; n < 4; ++n) {
      int col = c0 + wc * 64 + n * 16 + lr;
      float bv = bias[col];
#pragma unroll
      for (int m = 0; m < 4; ++m) {
#pragma unroll
        for (int r = 0; r < 4; ++r) {
          int row = r0 + wr * 64 + m * 16 + lg * 4 + r;
          float v = (acc[m][n][r] + bv) * scale;
          if (RELU) v = fmaxf(v, 0.f);
          out[(size_t)row * DM_ + col] = f2bf(v);
        }
      }
    }
  } else {
    // transposed write: out = Vt [B][DM][S]; block lies in one batch
    const int bb = r0 / S_;
    const int sbase = r0 - bb * S_ + wr * 64 + lg * 4;
#pragma unroll
    for (int n = 0; n < 4; ++n) {
      int col = c0 + wc * 64 + n * 16 + lr;
      float bv = bias[col];
#pragma unroll
      for (int m = 0; m < 4; ++m) {
        ushort4 o;
#pragma unroll
        for (int r = 0; r < 4; ++r) {
          float v = acc[m][n][r] + bv;
          ((unsigned short*)&o)[r] = f2bf(v);
        }
        *(ushort4*)&out[((size_t)bb * DM_ + col) * S_ + sbase + m * 16] = o;
      }
    }
  }
}

// ---------------- GEMM + bias + residual + LayerNorm epilogue (16-row, BK=64) --
// Residual chain in bf16. NLN==2: out bf16 only; NLN==1: out fp32 (final).
template<int NLN>
__global__ __launch_bounds__(256) void gemm_ln_kernel(
    const unsigned short* __restrict__ A,
    const unsigned short* __restrict__ Wt,
    const float* __restrict__ bias,
    const unsigned short* __restrict__ res,   // [M][256] bf16
    const float* __restrict__ gA, const float* __restrict__ bA,
    const float* __restrict__ gB, const float* __restrict__ bB,
    float* __restrict__ outF,
    unsigned short* __restrict__ outB) {
  const int tid = threadIdx.x;
  const int w = tid >> 6, l = tid & 63;
  const int lr = l & 15, lg = l >> 4;
  const int r0 = blockIdx.x * 16;

  __shared__ __align__(16) unsigned short Bs[2][256 * 64];  // 32KB each
  __shared__ __align__(16) unsigned short As[2][16 * 64];   // 2KB each
  __shared__ float ex[16][4][2];

  f32x4 acc[4];
#pragma unroll
  for (int n = 0; n < 4; ++n) acc[n] = f32x4_zero();

  auto stage = [&](int buf, int k0) {
#pragma unroll
    for (int p = 0; p < 8; ++p) {        // B: 2048 chunks (256 rows x 8 slots)
      int c = (w * 8 + p) * 64 + l;
      int row = c >> 3, sl = c & 7;
      gload_lds16(Wt + (size_t)row * 512 + k0 + ((sl ^ (row & 7)) * 8),
                  &Bs[buf][(w * 8 + p) * 64 * 8]);
    }
    if (w == 0) {                         // A: 128 chunks (16 rows x 8 slots)
#pragma unroll
      for (int p = 0; p < 2; ++p) {
        int c = p * 64 + l;
        int row = c >> 3, sl = c & 7;
        gload_lds16(A + (size_t)(r0 + row) * 512 + k0 + ((sl ^ (row & 7)) * 8),
                    &As[buf][p * 64 * 8]);
      }
    }
  };

  stage(0, 0);
  __syncthreads();

  for (int tt = 0; tt < 8; tt += 2) {
#pragma unroll
    for (int u = 0; u < 2; ++u) {
      const int t = tt + u;
      if (t + 1 < 8) stage(u ^ 1, (t + 1) * 64);
      const unsigned short* BB = &Bs[u][0];
      const unsigned short* AB = &As[u][0];
#pragma unroll
      for (int kk = 0; kk < 2; ++kk) {
        bf16x8 a = *(const bf16x8*)&AB[lr * 64 + (((kk * 4 + lg) ^ (lr & 7)) * 8)];
#pragma unroll
        for (int n = 0; n < 4; ++n) {
          int row = w * 64 + n * 16 + lr;
          bf16x8 b = *(const bf16x8*)&BB[row * 64 + (((kk * 4 + lg) ^ (row & 7)) * 8)];
          acc[n] = MFMA16(a, b, acc[n]);
        }
      }
      __syncthreads();
    }
  }

  f32x4 rv[4];
#pragma unroll
  for (int n = 0; n < 4; ++n) {
    int col = w * 64 + n * 16 + lr;
    float bv = bias[col];
#pragma unroll
    for (int r = 0; r < 4; ++r) {
      int row = r0 + lg * 4 + r;
      float rr = bf2f(res[(size_t)row * 256 + col]);
      rv[n][r] = rr;
      acc[n][r] += bv + rr;
    }
  }

  auto ln_stats = [&](float* mu, float* rs) {
    float s1[4], s2[4];
#pragma unroll
    for (int r = 0; r < 4; ++r) {
      float a1 = 0.f, a2 = 0.f;
#pragma unroll
      for (int n = 0; n < 4; ++n) { float v = acc[n][r]; a1 += v; a2 += v * v; }
#pragma unroll
      for (int off = 1; off < 16; off <<= 1) {
        a1 += __shfl_xor(a1, off);
        a2 += __shfl_xor(a2, off);
      }
      s1[r] = a1; s2[r] = a2;
    }
    if (lr == 0) {
#pragma unroll
      for (int r = 0; r < 4; ++r) {
        ex[lg * 4 + r][w][0] = s1[r];
        ex[lg * 4 + r][w][1] = s2[r];
      }
    }
    __syncthreads();
#pragma unroll
    for (int r = 0; r < 4; ++r) {
      int row = lg * 4 + r;
      float t1 = ex[row][0][0] + ex[row][1][0] + ex[row][2][0] + ex[row][3][0];
      float t2 = ex[row][0][1] + ex[row][1][1] + ex[row][2][1] + ex[row][3][1];
      float m = t1 * (1.f / 256.f);
      float var = t2 * (1.f / 256.f) - m * m;
      mu[r] = m;
      rs[r] = rsqrtf(var + 1e-6f);
    }
  };

  float mu[4], rs[4];
  ln_stats(mu, rs);

  if constexpr (NLN == 2) {
#pragma unroll
    for (int n = 0; n < 4; ++n) {
      int col = w * 64 + n * 16 + lr;
      float g = gA[col], bb = bA[col];
#pragma unroll
      for (int r = 0; r < 4; ++r) {
        float t1 = (acc[n][r] - mu[r]) * rs[r] * g + bb;
        acc[n][r] = rv[n][r] + t1;
      }
    }
    __syncthreads();
    float mu2[4], rs2[4];
    ln_stats(mu2, rs2);
#pragma unroll
    for (int n = 0; n < 4; ++n) {
      int col = w * 64 + n * 16 + lr;
      float g = gB[col], bb = bB[col];
#pragma unroll
      for (int r = 0; r < 4; ++r) {
        int row = r0 + lg * 4 + r;
        float o = (acc[n][r] - mu2[r]) * rs2[r] * g + bb;
        outB[(size_t)row * 256 + col] = f2bf(o);
      }
    }
  } else {
#pragma unroll
    for (int n = 0; n < 4; ++n) {
      int col = w * 64 + n * 16 + lr;
      float g = gA[col], bb = bA[col];
#pragma unroll
      for (int r = 0; r < 4; ++r) {
        int row = r0 + lg * 4 + r;
        float o = (acc[n][r] - mu[r]) * rs[r] * g + bb;
        outF[(size_t)row * 256 + col] = o;
      }
    }
  }
}

// ---------------- Flash attention v10 (r15, measured best: 58.7us) ----------
template<bool MASKED>
__global__ __launch_bounds__(256) void flash_kernel(
    const unsigned short* __restrict__ Q,
    const unsigned short* __restrict__ Kg,
    const unsigned short* __restrict__ Vt,
    const int* __restrict__ mask,
    unsigned short* __restrict__ O) {
  __shared__ __align__(16) unsigned short lds[2][2][64 * 64];
  const int tid = threadIdx.x;
  const int w = tid >> 6, l = tid & 63;
  const int q32 = l & 31, hi = l >> 5;
  const int id = blockIdx.x;
  const int g = (id & 7) * 64 + (id >> 3);
  const int bh = g >> 4, xblk = g & 15;
  const int b = bh >> 3, h = bh & 7;
  const size_t bS = (size_t)b * S_;
  const int q0 = xblk * 128 + w * 32;

  bf16x8 qf[4];
  {
    const unsigned short* qp = Q + (bS + q0 + q32) * DM_ + h * DH_;
#pragma unroll
    for (int c = 0; c < 4; ++c) qf[c] = *(const bf16x8*)(qp + c * 16 + hi * 8);
  }
  bf16x8 ones;
#pragma unroll
  for (int j = 0; j < 8; ++j) ones[j] = (short)0x3F80;   // bf16 1.0

  f32x16 o0 = f32x16_zero(), o1 = f32x16_zero(), lacc = f32x16_zero();
  float m = -1e30f;

  auto stage = [&](int buf, int kv0) {
#pragma unroll
    for (int p = 0; p < 2; ++p) {
      int i = w * 2 + p;                 // 0..7
      int row = i * 8 + (l >> 3);
      int slot = l & 7;
      gload_lds16(Kg + (bS + kv0 + row) * DM_ + h * DH_ + ((slot ^ (row & 7)) * 8),
                  &lds[buf][0][i * 8 * 64]);
      gload_lds16(Vt + ((size_t)b * DM_ + h * DH_ + row) * S_ + kv0 + ((slot ^ (row & 7)) * 8),
                  &lds[buf][1][i * 8 * 64]);
    }
  };

  stage(0, 0);
  int mvCur = 1;
  if (MASKED) mvCur = mask[bS + l];
  __syncthreads();

  const int NT = S_ / 64;   // 32, even
  for (int tt = 0; tt < NT; tt += 2) {
#pragma unroll
    for (int u = 0; u < 2; ++u) {        // u = buffer index (compile-time)
      const int t = tt + u;
      int mvNext = 1;
      if (t + 1 < NT) {
        stage(u ^ 1, (t + 1) * 64);
        if (MASKED) mvNext = mask[bS + (t + 1) * 64 + l];
      }
      u64 bits = 0;
      if (MASKED) bits = __ballot(mvCur != 0);

      const unsigned short* KB = &lds[u][0][0];
      const unsigned short* VB = &lds[u][1][0];

      f32x16 sc[2];
      __builtin_amdgcn_s_setprio(1);
#pragma unroll
      for (int kt = 0; kt < 2; ++kt) {
        f32x16 s = f32x16_zero();
#pragma unroll
        for (int c = 0; c < 4; ++c) {
          int row = kt * 32 + q32;
          int slot = (c * 2 + hi) ^ (row & 7);
          bf16x8 kf = *(const bf16x8*)&KB[row * 64 + slot * 8];
          s = MFMA32(kf, qf[c], s);
        }
        if (MASKED) {
          u32 valid = (u32)(bits >> (kt * 32 + q32)) & 1u;
          u32 mfw = valid ? 0u : 0xC080C080u;   // bf16 -4.0 pair; 16 k-slots -> -64
          union { u32 u[4]; bf16x8 v; } mf;
          mf.u[0] = mfw; mf.u[1] = mfw; mf.u[2] = mfw; mf.u[3] = mfw;
          s = MFMA32(mf.v, ones, s);
        }
        sc[kt] = s;
      }
      __builtin_amdgcn_s_setprio(0);

      float tm;
      {
        float r01;
#pragma unroll
        for (int kt = 0; kt < 2; ++kt) {
          float m0 = max3f(sc[kt][0], sc[kt][1], sc[kt][2]);
          float m1 = max3f(sc[kt][3], sc[kt][4], sc[kt][5]);
          float m2 = max3f(sc[kt][6], sc[kt][7], sc[kt][8]);
          float m3 = max3f(sc[kt][9], sc[kt][10], sc[kt][11]);
          float m4 = max3f(sc[kt][12], sc[kt][13], sc[kt][14]);
          float r = fmaxf(max3f(max3f(m0, m1, m2), m3, m4), sc[kt][15]);
          if (kt == 0) r01 = r; else r01 = fmaxf(r01, r);
        }
        tm = fmaxf(r01, __shfl_xor(r01, 32));
      }

      if (__any(tm > m + 11.5f)) {       // defer-max, THR = 11.5 bits
        float mn = fmaxf(m, tm);
        float fac = exp2_asm(m - mn);
        m = mn;
#pragma unroll
        for (int i = 0; i < 16; ++i) {
          int rq = (i & 3) + 8 * (i >> 2) + 4 * hi;
          float fr = __shfl(fac, rq);
          o0[i] *= fr;
          o1[i] *= fr;
          lacc[i] *= fr;
        }
      }

      float pv[2][16];
#pragma unroll
      for (int kt = 0; kt < 2; ++kt)
#pragma unroll
        for (int i = 0; i < 16; ++i) pv[kt][i] = exp2_asm(sc[kt][i] - m);

      u32 w8[2][8];
#pragma unroll
      for (int kt = 0; kt < 2; ++kt)
#pragma unroll
        for (int j = 0; j < 8; ++j)
          w8[kt][j] = cvtpk_bf16(pv[kt][2 * j], pv[kt][2 * j + 1]);

      __builtin_amdgcn_s_setprio(1);
#pragma unroll
      for (int kt = 0; kt < 2; ++kt) {
#pragma unroll
        for (int kc = 0; kc < 2; ++kc) {
          v2i r0 = __builtin_amdgcn_permlane32_swap((int)w8[kt][4 * kc + 0],
                                                    (int)w8[kt][4 * kc + 2], false, false);
          v2i r1 = __builtin_amdgcn_permlane32_swap((int)w8[kt][4 * kc + 1],
                                                    (int)w8[kt][4 * kc + 3], false, false);
          union { u32 u[4]; bf16x8 v; } af;
          af.u[0] = (u32)r0.x; af.u[1] = (u32)r1.x; af.u[2] = (u32)r0.y; af.u[3] = (u32)r1.y;
          {
            int row = q32;
            int slot = (kt * 4 + kc * 2 + hi) ^ (row & 7);
            bf16x8 vf = *(const bf16x8*)&VB[row * 64 + slot * 8];
            o0 = MFMA32(af.v, vf, o0);
          }
          {
            int row = 32 + q32;
            int slot = (kt * 4 + kc * 2 + hi) ^ (row & 7);
            bf16x8 vf = *(const bf16x8*)&VB[row * 64 + slot * 8];
            o1 = MFMA32(af.v, vf, o1);
          }
          lacc = MFMA32(af.v, ones, lacc);   // row-sum on the MFMA pipe
        }
      }
      __builtin_amdgcn_s_setprio(0);
      __syncthreads();
      mvCur = mvNext;
    }
  }

#pragma unroll
  for (int i = 0; i < 16; ++i) {
    int rq = (i & 3) + 8 * (i >> 2) + 4 * hi;
    float inv = __builtin_amdgcn_rcpf(lacc[i]);
    int row = q0 + rq;
    O[(bS + row) * DM_ + h * DH_ + q32] = f2bf(o0[i] * inv);
    O[(bS + row) * DM_ + h * DH_ + 32 + q32] = f2bf(o1[i] * inv);
  }
}

// ---------------- host ----------------
extern "C" void kernel_launch(void* const* d_in, const int* in_sizes, int n_in,
                              void* d_out, int out_size, void* d_ws, size_t ws_size,
                              hipStream_t stream) {
  const float* x     = (const float*)d_in[0];
  const float* eo    = (const float*)d_in[1];
  const int*   tmask = (const int*)d_in[2];
  const float* m1_wq = (const float*)d_in[4];  const float* m1_bq = (const float*)d_in[5];
  const float* m1_wk = (const float*)d_in[6];  const float* m1_bk = (const float*)d_in[7];
  const float* m1_wv = (const float*)d_in[8];  const float* m1_bv = (const float*)d_in[9];
  const float* m1_w2 = (const float*)d_in[10]; const float* m1_b2 = (const float*)d_in[11];
  const float* m1_g  = (const float*)d_in[12]; const float* m1_b  = (const float*)d_in[13];
  const float* m2_wq = (const float*)d_in[14]; const float* m2_bq = (const float*)d_in[15];
  const float* m2_wk = (const float*)d_in[16]; const float* m2_bk = (const float*)d_in[17];
  const float* m2_wv = (const float*)d_in[18]; const float* m2_bv = (const float*)d_in[19];
  const float* m2_w2 = (const float*)d_in[20]; const float* m2_b2 = (const float*)d_in[21];
  const float* m2_g  = (const float*)d_in[22]; const float* m2_b  = (const float*)d_in[23];
  const float* ln1_g = (const float*)d_in[24]; const float* ln1_b = (const float*)d_in[25];
  const float* ln2_g = (const float*)d_in[26]; const float* ln2_b = (const float*)d_in[27];
  const float* ln3_g = (const float*)d_in[28]; const float* ln3_b = (const float*)d_in[29];
  const float* f_w1  = (const float*)d_in[30]; const float* f_b1  = (const float*)d_in[31];
  const float* f_w2  = (const float*)d_in[32]; const float* f_b2  = (const float*)d_in[33];

  char* ws = (char*)d_ws;
  size_t off = 0;
  auto alloc = [&](size_t bytes) -> void* {
    void* p = ws + off;
    off += (bytes + 255) & ~(size_t)255;
    return p;
  };
  unsigned short* wt[10];
  for (int i = 0; i < 10; ++i) wt[i] = (unsigned short*)alloc(131072 * 2);
  unsigned short* xb  = (unsigned short*)alloc((size_t)M_ * DIN_ * 2);
  unsigned short* eb  = (unsigned short*)alloc((size_t)M_ * DIN_ * 2);
  unsigned short* Qb  = (unsigned short*)alloc((size_t)M_ * DM_ * 2);
  unsigned short* Kb  = (unsigned short*)alloc((size_t)M_ * DM_ * 2);
  unsigned short* AOb = (unsigned short*)alloc((size_t)M_ * DM_ * 2);
  unsigned short* X1b = (unsigned short*)alloc((size_t)M_ * DIN_ * 2);
  unsigned short* X2b = (unsigned short*)alloc((size_t)M_ * DIN_ * 2);
  unsigned short* VtA = (unsigned short*)alloc((size_t)M_ * DM_ * 2);  // [B][512][2048]
  unsigned short* VtB = (unsigned short*)alloc((size_t)M_ * DM_ * 2);
  unsigned short* Hb  = Qb;                      // dead by FFN stage

  int n4 = M_ * DIN_ / 4;
  cast_bf16_kernel<<<dim3(n4 / 256, 2), 256, 0, stream>>>(x, eo, xb, eb, n4);

  WtDesc wd;
  const float* srcs[10] = {m1_wq, m1_wk, m1_wv, m1_w2, m2_wq, m2_wk, m2_wv, m2_w2, f_w1, f_w2};
  int kss[10]           = {8,     8,     8,     9,     8,     8,     8,     9,     8,    9};
  for (int i = 0; i < 10; ++i) { wd.src[i] = srcs[i]; wd.dst[i] = wt[i]; wd.ks[i] = kss[i]; }
  prep_w_kernel<<<dim3(32, 10), 256, 0, stream>>>(wd);

  const int FG = (S_ / 128) * H_ * B_;   // 512 flat blocks, XCD-grouped in-kernel
  const float QSCALE = 0.125f * 1.44269504088896f;   // 1/sqrt(DH) * log2(e)

  // ---- stage A: masked self-attention (V written transposed by GEMM) ----
  gemm_tiled_kernel<256, false><<<dim3(M_ / 128, 12), 256, 0, stream>>>(
      xb, xb, xb, wt[0], wt[1], wt[2], m1_bq, m1_bk, m1_bv, Qb, Kb, VtA, QSCALE, 2);
  flash_kernel<true><<<FG, 256, 0, stream>>>(Qb, Kb, VtA, tmask, AOb);
  gemm_ln_kernel<2><<<M_ / 16, 256, 0, stream>>>(AOb, wt[3], m1_b2, xb,
                                                 m1_g, m1_b, ln1_g, ln1_b, nullptr, X1b);
  // ---- stage B: cross-attention; Q from X1b, K/V from eb (V transposed) ----
  gemm_tiled_kernel<256, false><<<dim3(M_ / 128, 12), 256, 0, stream>>>(
      X1b, eb, eb, wt[4], wt[5], wt[6], m2_bq, m2_bk, m2_bv, Qb, Kb, VtB, QSCALE, 2);
  flash_kernel<false><<<FG, 256, 0, stream>>>(Qb, Kb, VtB, nullptr, AOb);
  gemm_ln_kernel<2><<<M_ / 16, 256, 0, stream>>>(AOb, wt[7], m2_b2, X1b,
                                                 m2_g, m2_b, ln2_g, ln2_b, nullptr, X2b);
  // ---- stage C: FFN ----
  gemm_tiled_kernel<256, true><<<dim3(M_ / 128, 4), 256, 0, stream>>>(
      X2b, X2b, X2b, wt[8], wt[8], wt[8], f_b1, f_b1, f_b1, Hb, Hb, Hb, 1.f, -1);
  gemm_ln_kernel<1><<<M_ / 16, 256, 0, stream>>>(Hb, wt[9], f_b2, X2b,
                                                 ln3_g, ln3_b, nullptr, nullptr,
                                                 (float*)d_out, nullptr);
}

// Round 20
// 184.982 us; speedup vs baseline: 1.3011x; 1.0266x over previous
//
#include <hip/hip_runtime.h>
#include <hip/hip_bf16.h>

#define B_ 4
#define S_ 2048
#define DIN_ 256
#define DM_ 512
#define H_ 8
#define DH_ 64
#define M_ (B_*S_)

typedef short bf16x8 __attribute__((ext_vector_type(8)));
typedef float f32x4 __attribute__((ext_vector_type(4)));
typedef float f32x16 __attribute__((ext_vector_type(16)));
typedef int v2i __attribute__((ext_vector_type(2)));
typedef unsigned int u32;
typedef unsigned long long u64;

#define MFMA16(a,b,c) __builtin_amdgcn_mfma_f32_16x16x32_bf16((a),(b),(c),0,0,0)
#define MFMA32(a,b,c) __builtin_amdgcn_mfma_f32_32x32x16_bf16((a),(b),(c),0,0,0)

__device__ __forceinline__ unsigned short f2bf(float f) {
  union { float f; unsigned u; } v; v.f = f;
  unsigned r = v.u + 0x7fffu + ((v.u >> 16) & 1u);
  return (unsigned short)(r >> 16);
}
__device__ __forceinline__ float bf2f(unsigned short b) {
  union { unsigned u; float f; } v; v.u = (unsigned)b << 16; return v.f;
}
__device__ __forceinline__ f32x4 f32x4_zero() { f32x4 v = {0.f,0.f,0.f,0.f}; return v; }
__device__ __forceinline__ f32x16 f32x16_zero() {
  f32x16 v;
#pragma unroll
  for (int i = 0; i < 16; ++i) v[i] = 0.f;
  return v;
}
__device__ __forceinline__ u32 cvtpk_bf16(float lo, float hi) {
  u32 r; asm("v_cvt_pk_bf16_f32 %0, %1, %2" : "=v"(r) : "v"(lo), "v"(hi)); return r;
}
__device__ __forceinline__ float exp2_asm(float x) {
  float r; asm("v_exp_f32 %0, %1" : "=v"(r) : "v"(x)); return r;
}
__device__ __forceinline__ float max3f(float a, float b, float c) {
  return fmaxf(fmaxf(a, b), c);   // clang fuses to v_max3_f32
}
__device__ __forceinline__ void gload_lds16(const void* g, void* l) {
  __builtin_amdgcn_global_load_lds((const __attribute__((address_space(1))) unsigned int*)g,
                                   (__attribute__((address_space(3))) unsigned int*)l,
                                   16, 0, 0);
}

// ---------------- fp32 -> bf16 cast (two tensors, one launch) ----------------
__global__ void cast_bf16_kernel(const float* __restrict__ inA,
                                 const float* __restrict__ inB,
                                 unsigned short* __restrict__ outA,
                                 unsigned short* __restrict__ outB, int n4) {
  const float* in = blockIdx.y ? inB : inA;
  unsigned short* out = blockIdx.y ? outB : outA;
  int i = blockIdx.x * blockDim.x + threadIdx.x;
  if (i < n4) {
    float4 v = ((const float4*)in)[i];
    ushort4 o;
    o.x = f2bf(v.x); o.y = f2bf(v.y); o.z = f2bf(v.z); o.w = f2bf(v.w);
    ((ushort4*)out)[i] = o;
  }
}

// ---------------- weight prep v2: W[K][N] fp32 -> Wt[N][K] bf16 --------------
struct WtDesc {
  const float* src[10];
  unsigned short* dst[10];
  int ks[10];
};
__global__ __launch_bounds__(256) void prep_w_kernel(WtDesc d) {
  __shared__ float T[64][65];
  const int m = blockIdx.y;
  const int ks = d.ks[m];
  const int K = 1 << ks;                  // inner dim of Wt (rows of src)
  const int N = 131072 >> ks;             // cols of src
  const int nk = K >> 6;
  const int kt = blockIdx.x % nk, nt = blockIdx.x / nk;
  const int k0 = kt * 64, n0 = nt * 64;
  const int tid = threadIdx.x;
  const float* src = d.src[m];
  unsigned short* dst = d.dst[m];

  const int rk = tid >> 4, rn = (tid & 15) * 4;
#pragma unroll
  for (int p = 0; p < 4; ++p) {
    int kk = p * 16 + rk;
    float4 v = *(const float4*)&src[(size_t)(k0 + kk) * N + n0 + rn];
    T[kk][rn] = v.x; T[kk][rn + 1] = v.y; T[kk][rn + 2] = v.z; T[kk][rn + 3] = v.w;
  }
  __syncthreads();

  const int wn = tid >> 3, wk = (tid & 7) * 8;
#pragma unroll
  for (int p = 0; p < 2; ++p) {
    int nn = p * 32 + wn;
    bf16x8 o;
#pragma unroll
    for (int j = 0; j < 8; ++j) o[j] = (short)f2bf(T[wk + j][nn]);
    *(bf16x8*)&dst[(size_t)(n0 + nn) * K + k0 + wk] = o;
  }
}

// ---------------- tiled GEMM: 128x128 tile, BK=64 ----------------
// Per-sel A pointer so independent GEMMs share one launch. sel == trsel
// writes Vt layout [B][DM][S] (fused V-transpose). 128B LDS rows are
// XOR-swizzled (slot^=row&7) with inverse-swizzled gload source; 32 MFMA
// per wave per barrier period (4 or 8 k-iterations). Parity-unrolled.
template<int K, bool RELU>
__global__ __launch_bounds__(256) void gemm_tiled_kernel(
    const unsigned short* __restrict__ A0, const unsigned short* __restrict__ A1,
    const unsigned short* __restrict__ A2,
    const unsigned short* __restrict__ W0, const unsigned short* __restrict__ W1,
    const unsigned short* __restrict__ W2,
    const float* __restrict__ b0, const float* __restrict__ b1, const float* __restrict__ b2,
    unsigned short* __restrict__ o0, unsigned short* __restrict__ o1,
    unsigned short* __restrict__ o2, float scale0, int trsel) {
  const int sel = blockIdx.y >> 2;
  const unsigned short* A = sel == 0 ? A0 : (sel == 1 ? A1 : A2);
  const unsigned short* Wt = sel == 0 ? W0 : (sel == 1 ? W1 : W2);
  const float* bias = sel == 0 ? b0 : (sel == 1 ? b1 : b2);
  unsigned short* out = sel == 0 ? o0 : (sel == 1 ? o1 : o2);
  const float scale = sel == 0 ? scale0 : 1.f;

  const int tid = threadIdx.x;
  const int w = tid >> 6, l = tid & 63;
  const int lr = l & 15, lg = l >> 4;
  const int wr = w >> 1, wc = w & 1;
  const int r0 = blockIdx.x * 128;
  const int c0 = (blockIdx.y & 3) * 128;

  __shared__ __align__(16) unsigned short As[2][128 * 64];   // 16KB each
  __shared__ __align__(16) unsigned short Bs[2][128 * 64];

  f32x4 acc[4][4];
#pragma unroll
  for (int m = 0; m < 4; ++m)
#pragma unroll
    for (int n = 0; n < 4; ++n) acc[m][n] = f32x4_zero();

  auto stage = [&](int buf, int k0) {
#pragma unroll
    for (int p = 0; p < 4; ++p) {
      int c = w * 256 + p * 64 + l;      // 1024 chunks of 16B each for A and B
      int row = c >> 3, sl = c & 7;
      gload_lds16(A + (size_t)(r0 + row) * K + k0 + ((sl ^ (row & 7)) * 8),
                  &As[buf][(w * 256 + p * 64) * 8]);
      gload_lds16(Wt + (size_t)(c0 + row) * K + k0 + ((sl ^ (row & 7)) * 8),
                  &Bs[buf][(w * 256 + p * 64) * 8]);
    }
  };

  stage(0, 0);
  __syncthreads();

  const int NT = K / 64;                 // 4 or 8, even
  for (int tt = 0; tt < NT; tt += 2) {
#pragma unroll
    for (int u = 0; u < 2; ++u) {
      const int t = tt + u;
      if (t + 1 < NT) stage(u ^ 1, (t + 1) * 64);
      const unsigned short* AB = &As[u][0];
      const unsigned short* BB = &Bs[u][0];
#pragma unroll
      for (int kk = 0; kk < 2; ++kk) {
        bf16x8 af[4], bf[4];
#pragma unroll
        for (int m = 0; m < 4; ++m) {
          int row = wr * 64 + m * 16 + lr;
          af[m] = *(const bf16x8*)&AB[row * 64 + (((kk * 4 + lg) ^ (row & 7)) * 8)];
        }
#pragma unroll
        for (int n = 0; n < 4; ++n) {
          int row = wc * 64 + n * 16 + lr;
          bf[n] = *(const bf16x8*)&BB[row * 64 + (((kk * 4 + lg) ^ (row & 7)) * 8)];
        }
#pragma unroll
        for (int m = 0; m < 4; ++m)
#pragma unroll
          for (int n = 0; n < 4; ++n)
            acc[m][n] = MFMA16(af[m], bf[n], acc[m][n]);
      }
      __syncthreads();
    }
  }

  if (sel != trsel) {
#pragma unroll
    for (int n = 0; n < 4; ++n) {
      int col = c0 + wc * 64 + n * 16 + lr;
      float bv = bias[col];
#pragma unroll
      for (int m = 0; m < 4; ++m) {
#pragma unroll
        for (int r = 0; r < 4; ++r) {
          int row = r0 + wr * 64 + m * 16 + lg * 4 + r;
          float v = (acc[m][n][r] + bv) * scale;
          if (RELU) v = fmaxf(v, 0.f);
          out[(size_t)row * DM_ + col] = f2bf(v);
        }
      }
    }
  } else {
    // transposed write: out = Vt [B][DM][S]; block lies in one batch
    const int bb = r0 / S_;
    const int sbase = r0 - bb * S_ + wr * 64 + lg * 4;
#pragma unroll
    for (int n = 0; n < 4; ++n) {
      int col = c0 + wc * 64 + n * 16 + lr;
      float bv = bias[col];
#pragma unroll
      for (int m = 0; m < 4; ++m) {
        ushort4 o;
#pragma unroll
        for (int r = 0; r < 4; ++r) {
          float v = acc[m][n][r] + bv;
          ((unsigned short*)&o)[r] = f2bf(v);
        }
        *(ushort4*)&out[((size_t)bb * DM_ + col) * S_ + sbase + m * 16] = o;
      }
    }
  }
}

// ---------------- GEMM + bias + residual + LayerNorm epilogue (16-row, BK=64) --
// Residual chain in bf16. NLN==2: out bf16 only; NLN==1: out fp32 (final).
template<int NLN>
__global__ __launch_bounds__(256) void gemm_ln_kernel(
    const unsigned short* __restrict__ A,
    const unsigned short* __restrict__ Wt,
    const float* __restrict__ bias,
    const unsigned short* __restrict__ res,   // [M][256] bf16
    const float* __restrict__ gA, const float* __restrict__ bA,
    const float* __restrict__ gB, const float* __restrict__ bB,
    float* __restrict__ outF,
    unsigned short* __restrict__ outB) {
  const int tid = threadIdx.x;
  const int w = tid >> 6, l = tid & 63;
  const int lr = l & 15, lg = l >> 4;
  const int r0 = blockIdx.x * 16;

  __shared__ __align__(16) unsigned short Bs[2][256 * 64];  // 32KB each
  __shared__ __align__(16) unsigned short As[2][16 * 64];   // 2KB each
  __shared__ float ex[16][4][2];

  f32x4 acc[4];
#pragma unroll
  for (int n = 0; n < 4; ++n) acc[n] = f32x4_zero();

  auto stage = [&](int buf, int k0) {
#pragma unroll
    for (int p = 0; p < 8; ++p) {        // B: 2048 chunks (256 rows x 8 slots)
      int c = (w * 8 + p) * 64 + l;
      int row = c >> 3, sl = c & 7;
      gload_lds16(Wt + (size_t)row * 512 + k0 + ((sl ^ (row & 7)) * 8),
                  &Bs[buf][(w * 8 + p) * 64 * 8]);
    }
    if (w == 0) {                         // A: 128 chunks (16 rows x 8 slots)
#pragma unroll
      for (int p = 0; p < 2; ++p) {
        int c = p * 64 + l;
        int row = c >> 3, sl = c & 7;
        gload_lds16(A + (size_t)(r0 + row) * 512 + k0 + ((sl ^ (row & 7)) * 8),
                    &As[buf][p * 64 * 8]);
      }
    }
  };

  stage(0, 0);
  __syncthreads();

  for (int tt = 0; tt < 8; tt += 2) {
#pragma unroll
    for (int u = 0; u < 2; ++u) {
      const int t = tt + u;
      if (t + 1 < 8) stage(u ^ 1, (t + 1) * 64);
      const unsigned short* BB = &Bs[u][0];
      const unsigned short* AB = &As[u][0];
#pragma unroll
      for (int kk = 0; kk < 2; ++kk) {
        bf16x8 a = *(const bf16x8*)&AB[lr * 64 + (((kk * 4 + lg) ^ (lr & 7)) * 8)];
#pragma unroll
        for (int n = 0; n < 4; ++n) {
          int row = w * 64 + n * 16 + lr;
          bf16x8 b = *(const bf16x8*)&BB[row * 64 + (((kk * 4 + lg) ^ (row & 7)) * 8)];
          acc[n] = MFMA16(a, b, acc[n]);
        }
      }
      __syncthreads();
    }
  }

  f32x4 rv[4];
#pragma unroll
  for (int n = 0; n < 4; ++n) {
    int col = w * 64 + n * 16 + lr;
    float bv = bias[col];
#pragma unroll
    for (int r = 0; r < 4; ++r) {
      int row = r0 + lg * 4 + r;
      float rr = bf2f(res[(size_t)row * 256 + col]);
      rv[n][r] = rr;
      acc[n][r] += bv + rr;
    }
  }

  auto ln_stats = [&](float* mu, float* rs) {
    float s1[4], s2[4];
#pragma unroll
    for (int r = 0; r < 4; ++r) {
      float a1 = 0.f, a2 = 0.f;
#pragma unroll
      for (int n = 0; n < 4; ++n) { float v = acc[n][r]; a1 += v; a2 += v * v; }
#pragma unroll
      for (int off = 1; off < 16; off <<= 1) {
        a1 += __shfl_xor(a1, off);
        a2 += __shfl_xor(a2, off);
      }
      s1[r] = a1; s2[r] = a2;
    }
    if (lr == 0) {
#pragma unroll
      for (int r = 0; r < 4; ++r) {
        ex[lg * 4 + r][w][0] = s1[r];
        ex[lg * 4 + r][w][1] = s2[r];
      }
    }
    __syncthreads();
#pragma unroll
    for (int r = 0; r < 4; ++r) {
      int row = lg * 4 + r;
      float t1 = ex[row][0][0] + ex[row][1][0] + ex[row][2][0] + ex[row][3][0];
      float t2 = ex[row][0][1] + ex[row][1][1] + ex[row][2][1] + ex[row][3][1];
      float m = t1 * (1.f / 256.f);
      float var = t2 * (1.f / 256.f) - m * m;
      mu[r] = m;
      rs[r] = rsqrtf(var + 1e-6f);
    }
  };

  float mu[4], rs[4];
  ln_stats(mu, rs);

  if constexpr (NLN == 2) {
#pragma unroll
    for (int n = 0; n < 4; ++n) {
      int col = w * 64 + n * 16 + lr;
      float g = gA[col], bb = bA[col];
#pragma unroll
      for (int r = 0; r < 4; ++r) {
        float t1 = (acc[n][r] - mu[r]) * rs[r] * g + bb;
        acc[n][r] = rv[n][r] + t1;
      }
    }
    __syncthreads();
    float mu2[4], rs2[4];
    ln_stats(mu2, rs2);
#pragma unroll
    for (int n = 0; n < 4; ++n) {
      int col = w * 64 + n * 16 + lr;
      float g = gB[col], bb = bB[col];
#pragma unroll
      for (int r = 0; r < 4; ++r) {
        int row = r0 + lg * 4 + r;
        float o = (acc[n][r] - mu2[r]) * rs2[r] * g + bb;
        outB[(size_t)row * 256 + col] = f2bf(o);
      }
    }
  } else {
#pragma unroll
    for (int n = 0; n < 4; ++n) {
      int col = w * 64 + n * 16 + lr;
      float g = gA[col], bb = bA[col];
#pragma unroll
      for (int r = 0; r < 4; ++r) {
        int row = r0 + lg * 4 + r;
        float o = (acc[n][r] - mu[r]) * rs[r] * g + bb;
        outF[(size_t)row * 256 + col] = o;
      }
    }
  }
}

// ---------------- Flash attention v10 (r15, measured best: 58.7us) ----------
template<bool MASKED>
__global__ __launch_bounds__(256) void flash_kernel(
    const unsigned short* __restrict__ Q,
    const unsigned short* __restrict__ Kg,
    const unsigned short* __restrict__ Vt,
    const int* __restrict__ mask,
    unsigned short* __restrict__ O) {
  __shared__ __align__(16) unsigned short lds[2][2][64 * 64];
  const int tid = threadIdx.x;
  const int w = tid >> 6, l = tid & 63;
  const int q32 = l & 31, hi = l >> 5;
  const int id = blockIdx.x;
  const int g = (id & 7) * 64 + (id >> 3);
  const int bh = g >> 4, xblk = g & 15;
  const int b = bh >> 3, h = bh & 7;
  const size_t bS = (size_t)b * S_;
  const int q0 = xblk * 128 + w * 32;

  bf16x8 qf[4];
  {
    const unsigned short* qp = Q + (bS + q0 + q32) * DM_ + h * DH_;
#pragma unroll
    for (int c = 0; c < 4; ++c) qf[c] = *(const bf16x8*)(qp + c * 16 + hi * 8);
  }
  bf16x8 ones;
#pragma unroll
  for (int j = 0; j < 8; ++j) ones[j] = (short)0x3F80;   // bf16 1.0

  f32x16 o0 = f32x16_zero(), o1 = f32x16_zero(), lacc = f32x16_zero();
  float m = -1e30f;

  auto stage = [&](int buf, int kv0) {
#pragma unroll
    for (int p = 0; p < 2; ++p) {
      int i = w * 2 + p;                 // 0..7
      int row = i * 8 + (l >> 3);
      int slot = l & 7;
      gload_lds16(Kg + (bS + kv0 + row) * DM_ + h * DH_ + ((slot ^ (row & 7)) * 8),
                  &lds[buf][0][i * 8 * 64]);
      gload_lds16(Vt + ((size_t)b * DM_ + h * DH_ + row) * S_ + kv0 + ((slot ^ (row & 7)) * 8),
                  &lds[buf][1][i * 8 * 64]);
    }
  };

  stage(0, 0);
  int mvCur = 1;
  if (MASKED) mvCur = mask[bS + l];
  __syncthreads();

  const int NT = S_ / 64;   // 32, even
  for (int tt = 0; tt < NT; tt += 2) {
#pragma unroll
    for (int u = 0; u < 2; ++u) {        // u = buffer index (compile-time)
      const int t = tt + u;
      int mvNext = 1;
      if (t + 1 < NT) {
        stage(u ^ 1, (t + 1) * 64);
        if (MASKED) mvNext = mask[bS + (t + 1) * 64 + l];
      }
      u64 bits = 0;
      if (MASKED) bits = __ballot(mvCur != 0);

      const unsigned short* KB = &lds[u][0][0];
      const unsigned short* VB = &lds[u][1][0];

      f32x16 sc[2];
      __builtin_amdgcn_s_setprio(1);
#pragma unroll
      for (int kt = 0; kt < 2; ++kt) {
        f32x16 s = f32x16_zero();
#pragma unroll
        for (int c = 0; c < 4; ++c) {
          int row = kt * 32 + q32;
          int slot = (c * 2 + hi) ^ (row & 7);
          bf16x8 kf = *(const bf16x8*)&KB[row * 64 + slot * 8];
          s = MFMA32(kf, qf[c], s);
        }
        if (MASKED) {
          u32 valid = (u32)(bits >> (kt * 32 + q32)) & 1u;
          u32 mfw = valid ? 0u : 0xC080C080u;   // bf16 -4.0 pair; 16 k-slots -> -64
          union { u32 u[4]; bf16x8 v; } mf;
          mf.u[0] = mfw; mf.u[1] = mfw; mf.u[2] = mfw; mf.u[3] = mfw;
          s = MFMA32(mf.v, ones, s);
        }
        sc[kt] = s;
      }
      __builtin_amdgcn_s_setprio(0);

      float tm;
      {
        float r01;
#pragma unroll
        for (int kt = 0; kt < 2; ++kt) {
          float m0 = max3f(sc[kt][0], sc[kt][1], sc[kt][2]);
          float m1 = max3f(sc[kt][3], sc[kt][4], sc[kt][5]);
          float m2 = max3f(sc[kt][6], sc[kt][7], sc[kt][8]);
          float m3 = max3f(sc[kt][9], sc[kt][10], sc[kt][11]);
          float m4 = max3f(sc[kt][12], sc[kt][13], sc[kt][14]);
          float r = fmaxf(max3f(max3f(m0, m1, m2), m3, m4), sc[kt][15]);
          if (kt == 0) r01 = r; else r01 = fmaxf(r01, r);
        }
        tm = fmaxf(r01, __shfl_xor(r01, 32));
      }

      if (__any(tm > m + 11.5f)) {       // defer-max, THR = 11.5 bits
        float mn = fmaxf(m, tm);
        float fac = exp2_asm(m - mn);
        m = mn;
#pragma unroll
        for (int i = 0; i < 16; ++i) {
          int rq = (i & 3) + 8 * (i >> 2) + 4 * hi;
          float fr = __shfl(fac, rq);
          o0[i] *= fr;
          o1[i] *= fr;
          lacc[i] *= fr;
        }
      }

      float pv[2][16];
#pragma unroll
      for (int kt = 0; kt < 2; ++kt)
#pragma unroll
        for (int i = 0; i < 16; ++i) pv[kt][i] = exp2_asm(sc[kt][i] - m);

      u32 w8[2][8];
#pragma unroll
      for (int kt = 0; kt < 2; ++kt)
#pragma unroll
        for (int j = 0; j < 8; ++j)
          w8[kt][j] = cvtpk_bf16(pv[kt][2 * j], pv[kt][2 * j + 1]);

      __builtin_amdgcn_s_setprio(1);
#pragma unroll
      for (int kt = 0; kt < 2; ++kt) {
#pragma unroll
        for (int kc = 0; kc < 2; ++kc) {
          v2i r0 = __builtin_amdgcn_permlane32_swap((int)w8[kt][4 * kc + 0],
                                                    (int)w8[kt][4 * kc + 2], false, false);
          v2i r1 = __builtin_amdgcn_permlane32_swap((int)w8[kt][4 * kc + 1],
                                                    (int)w8[kt][4 * kc + 3], false, false);
          union { u32 u[4]; bf16x8 v; } af;
          af.u[0] = (u32)r0.x; af.u[1] = (u32)r1.x; af.u[2] = (u32)r0.y; af.u[3] = (u32)r1.y;
          {
            int row = q32;
            int slot = (kt * 4 + kc * 2 + hi) ^ (row & 7);
            bf16x8 vf = *(const bf16x8*)&VB[row * 64 + slot * 8];
            o0 = MFMA32(af.v, vf, o0);
          }
          {
            int row = 32 + q32;
            int slot = (kt * 4 + kc * 2 + hi) ^ (row & 7);
            bf16x8 vf = *(const bf16x8*)&VB[row * 64 + slot * 8];
            o1 = MFMA32(af.v, vf, o1);
          }
          lacc = MFMA32(af.v, ones, lacc);   // row-sum on the MFMA pipe
        }
      }
      __builtin_amdgcn_s_setprio(0);
      __syncthreads();
      mvCur = mvNext;
    }
  }

#pragma unroll
  for (int i = 0; i < 16; ++i) {
    int rq = (i & 3) + 8 * (i >> 2) + 4 * hi;
    float inv = __builtin_amdgcn_rcpf(lacc[i]);
    int row = q0 + rq;
    O[(bS + row) * DM_ + h * DH_ + q32] = f2bf(o0[i] * inv);
    O[(bS + row) * DM_ + h * DH_ + 32 + q32] = f2bf(o1[i] * inv);
  }
}

// ---------------- host ----------------
extern "C" void kernel_launch(void* const* d_in, const int* in_sizes, int n_in,
                              void* d_out, int out_size, void* d_ws, size_t ws_size,
                              hipStream_t stream) {
  const float* x     = (const float*)d_in[0];
  const float* eo    = (const float*)d_in[1];
  const int*   tmask = (const int*)d_in[2];
  const float* m1_wq = (const float*)d_in[4];  const float* m1_bq = (const float*)d_in[5];
  const float* m1_wk = (const float*)d_in[6];  const float* m1_bk = (const float*)d_in[7];
  const float* m1_wv = (const float*)d_in[8];  const float* m1_bv = (const float*)d_in[9];
  const float* m1_w2 = (const float*)d_in[10]; const float* m1_b2 = (const float*)d_in[11];
  const float* m1_g  = (const float*)d_in[12]; const float* m1_b  = (const float*)d_in[13];
  const float* m2_wq = (const float*)d_in[14]; const float* m2_bq = (const float*)d_in[15];
  const float* m2_wk = (const float*)d_in[16]; const float* m2_bk = (const float*)d_in[17];
  const float* m2_wv = (const float*)d_in[18]; const float* m2_bv = (const float*)d_in[19];
  const float* m2_w2 = (const float*)d_in[20]; const float* m2_b2 = (const float*)d_in[21];
  const float* m2_g  = (const float*)d_in[22]; const float* m2_b  = (const float*)d_in[23];
  const float* ln1_g = (const float*)d_in[24]; const float* ln1_b = (const float*)d_in[25];
  const float* ln2_g = (const float*)d_in[26]; const float* ln2_b = (const float*)d_in[27];
  const float* ln3_g = (const float*)d_in[28]; const float* ln3_b = (const float*)d_in[29];
  const float* f_w1  = (const float*)d_in[30]; const float* f_b1  = (const float*)d_in[31];
  const float* f_w2  = (const float*)d_in[32]; const float* f_b2  = (const float*)d_in[33];

  char* ws = (char*)d_ws;
  size_t off = 0;
  auto alloc = [&](size_t bytes) -> void* {
    void* p = ws + off;
    off += (bytes + 255) & ~(size_t)255;
    return p;
  };
  unsigned short* wt[10];
  for (int i = 0; i < 10; ++i) wt[i] = (unsigned short*)alloc(131072 * 2);
  unsigned short* xb  = (unsigned short*)alloc((size_t)M_ * DIN_ * 2);
  unsigned short* eb  = (unsigned short*)alloc((size_t)M_ * DIN_ * 2);
  unsigned short* Qb  = (unsigned short*)alloc((size_t)M_ * DM_ * 2);
  unsigned short* Kb  = (unsigned short*)alloc((size_t)M_ * DM_ * 2);
  unsigned short* AOb = (unsigned short*)alloc((size_t)M_ * DM_ * 2);
  unsigned short* X1b = (unsigned short*)alloc((size_t)M_ * DIN_ * 2);
  unsigned short* X2b = (unsigned short*)alloc((size_t)M_ * DIN_ * 2);
  unsigned short* VtA = (unsigned short*)alloc((size_t)M_ * DM_ * 2);  // [B][512][2048]
  unsigned short* VtB = (unsigned short*)alloc((size_t)M_ * DM_ * 2);
  unsigned short* Hb  = Qb;                      // dead by FFN stage

  int n4 = M_ * DIN_ / 4;
  cast_bf16_kernel<<<dim3(n4 / 256, 2), 256, 0, stream>>>(x, eo, xb, eb, n4);

  WtDesc wd;
  const float* srcs[10] = {m1_wq, m1_wk, m1_wv, m1_w2, m2_wq, m2_wk, m2_wv, m2_w2, f_w1, f_w2};
  int kss[10]           = {8,     8,     8,     9,     8,     8,     8,     9,     8,    9};
  for (int i = 0; i < 10; ++i) { wd.src[i] = srcs[i]; wd.dst[i] = wt[i]; wd.ks[i] = kss[i]; }
  prep_w_kernel<<<dim3(32, 10), 256, 0, stream>>>(wd);

  const int FG = (S_ / 128) * H_ * B_;   // 512 flat blocks, XCD-grouped in-kernel
  const float QSCALE = 0.125f * 1.44269504088896f;   // 1/sqrt(DH) * log2(e)

  // ---- stage A: masked self-attention (V written transposed by GEMM) ----
  gemm_tiled_kernel<256, false><<<dim3(M_ / 128, 12), 256, 0, stream>>>(
      xb, xb, xb, wt[0], wt[1], wt[2], m1_bq, m1_bk, m1_bv, Qb, Kb, VtA, QSCALE, 2);
  flash_kernel<true><<<FG, 256, 0, stream>>>(Qb, Kb, VtA, tmask, AOb);
  gemm_ln_kernel<2><<<M_ / 16, 256, 0, stream>>>(AOb, wt[3], m1_b2, xb,
                                                 m1_g, m1_b, ln1_g, ln1_b, nullptr, X1b);
  // ---- stage B: cross-attention; Q from X1b, K/V from eb (V transposed) ----
  gemm_tiled_kernel<256, false><<<dim3(M_ / 128, 12), 256, 0, stream>>>(
      X1b, eb, eb, wt[4], wt[5], wt[6], m2_bq, m2_bk, m2_bv, Qb, Kb, VtB, QSCALE, 2);
  flash_kernel<false><<<FG, 256, 0, stream>>>(Qb, Kb, VtB, nullptr, AOb);
  gemm_ln_kernel<2><<<M_ / 16, 256, 0, stream>>>(AOb, wt[7], m2_b2, X1b,
                                                 m2_g, m2_b, ln2_g, ln2_b, nullptr, X2b);
  // ---- stage C: FFN ----
  gemm_tiled_kernel<256, true><<<dim3(M_ / 128, 4), 256, 0, stream>>>(
      X2b, X2b, X2b, wt[8], wt[8], wt[8], f_b1, f_b1, f_b1, Hb, Hb, Hb, 1.f, -1);
  gemm_ln_kernel<1><<<M_ / 16, 256, 0, stream>>>(Hb, wt[9], f_b2, X2b,
                                                 ln3_g, ln3_b, nullptr, nullptr,
                                                 (float*)d_out, nullptr);
}